// Round 1
// baseline (179.841 us; speedup 1.0000x reference)
//
#include <hip/hip_runtime.h>
#include <hip/hip_bf16.h>
#include <stdint.h>

// Problem constants
#define NHEADS 3
#define HID 64
#define NN 1024
#define BB 8
#define NROWS 8192   // B*N

using bf16x8 = __attribute__((ext_vector_type(8))) short;
using f32x4  = __attribute__((ext_vector_type(4))) float;

__device__ __forceinline__ unsigned short f2bf(float f) {
    unsigned u = __float_as_uint(f);
    u += 0x7fff + ((u >> 16) & 1);          // RNE
    return (unsigned short)(u >> 16);
}
__device__ __forceinline__ float fast_exp2(float x) {
    return __builtin_amdgcn_exp2f(x);
}
#define LOG2E 1.44269504f

// ---------------------------------------------------------------------------
// Setup: pack adjacency bits, bf16-convert/transpose weights, pad x, precompute
// Wsd = W @ blockdiag(a_src|a_dst) so s,d come out of the proj MFMA directly.
// Grid: 1024 blocks x 256 threads.
// ---------------------------------------------------------------------------
__global__ __launch_bounds__(256) void setup_kernel(
    const float* __restrict__ x, const int* __restrict__ adj, const float* __restrict__ h_prev,
    const float* __restrict__ W0, const float* __restrict__ as0, const float* __restrict__ ad0,
    const float* __restrict__ W1, const float* __restrict__ as1, const float* __restrict__ ad1,
    const float* __restrict__ W2, const float* __restrict__ as2, const float* __restrict__ ad2,
    const float* __restrict__ gwi, const float* __restrict__ gwh,
    const float* __restrict__ Wa1, const float* __restrict__ Wc1,
    unsigned long long* __restrict__ maskbits, unsigned short* __restrict__ xpad,
    unsigned short* __restrict__ hp16,
    unsigned short* __restrict__ W0Tp, unsigned short* __restrict__ W1T, unsigned short* __restrict__ W2T,
    unsigned short* __restrict__ wi16, unsigned short* __restrict__ wh16,
    unsigned short* __restrict__ Wa1T, unsigned short* __restrict__ Wc1T,
    unsigned short* __restrict__ Wsd0, unsigned short* __restrict__ Wsd1, unsigned short* __restrict__ Wsd2)
{
    int tid  = blockIdx.x * 256 + threadIdx.x;   // 0 .. 262143
    int lane = threadIdx.x & 63;
    int wv   = tid >> 6;                         // global wave id 0..4095

    // 1) adjacency -> bitmask: 16384 u64 words, 4 per wave
    #pragma unroll
    for (int i = 0; i < 4; ++i) {
        int w   = wv * 4 + i;                    // word index
        int row = w >> 4, wc = w & 15;
        int j   = wc * 64 + lane;
        unsigned long long m = __ballot(adj[row * 1024 + j] > 0);
        if (lane == 0) maskbits[w] = m;
    }
    // 2) x padded to [8192][32] bf16 (k<3 real)
    {
        int n = tid >> 5, k = tid & 31;
        xpad[tid] = (k < 3) ? f2bf(x[n * 3 + k]) : (unsigned short)0;
    }
    // 3) h_prev bf16 copy (524288 els, 2/thread)
    hp16[tid]          = f2bf(h_prev[tid]);
    hp16[tid + 262144] = f2bf(h_prev[tid + 262144]);
    // 4) W1T/W2T [192][64] transposed; gru wi/wh already [n][k], just convert
    if (tid < 12288) {
        int n = tid >> 6, k = tid & 63;
        W1T[tid]  = f2bf(W1[k * 192 + n]);
        W2T[tid]  = f2bf(W2[k * 192 + n]);
        wi16[tid] = f2bf(gwi[tid]);
        wh16[tid] = f2bf(gwh[tid]);
    }
    // 5) W0T padded [192][32]
    if (tid < 6144) {
        int n = tid >> 5, k = tid & 31;
        W0Tp[tid] = (k < 3) ? f2bf(W0[k * 192 + n]) : (unsigned short)0;
    }
    // 6) Wa1T/Wc1T [32][64]
    if (tid < 2048) {
        int n = tid >> 6, k = tid & 63;
        Wa1T[tid] = f2bf(Wa1[k * 32 + n]);
        Wc1T[tid] = f2bf(Wc1[k * 32 + n]);
    }
    // 7) Wsd: [16 cols][K] bf16; col c = 2h+isdst -> sum_f W[k][h*64+f]*a[h][f]
    if (tid < 16 * 32) {   // layer 0, K=32 (k<3 real)
        int c = tid >> 5, k = tid & 31;
        float v = 0.f;
        if (c < 6 && k < 3) {
            int h = c >> 1; const float* a = (c & 1) ? ad0 : as0;
            for (int f = 0; f < 64; ++f) v += W0[k * 192 + h * 64 + f] * a[h * 64 + f];
        }
        Wsd0[tid] = f2bf(v);
    }
    if (tid < 16 * 64) {   // layers 1,2, K=64
        int c = tid >> 6, k = tid & 63;
        float v1 = 0.f, v2 = 0.f;
        if (c < 6) {
            int h = c >> 1;
            const float* a1 = (c & 1) ? ad1 : as1;
            const float* a2 = (c & 1) ? ad2 : as2;
            for (int f = 0; f < 64; ++f) {
                v1 += W1[k * 192 + h * 64 + f] * a1[h * 64 + f];
                v2 += W2[k * 192 + h * 64 + f] * a2[h * 64 + f];
            }
        }
        Wsd1[tid] = f2bf(v1);
        Wsd2[tid] = f2bf(v2);
    }
}

// ---------------------------------------------------------------------------
// Projection: Wh = A(32xK) @ W(Kx192), plus s/d via the Wsd tile.
// Writes VT bf16 [b][h][f][n] (transposed for attn B-frags), st/dt f32 [b][h][n].
// Grid 256 = (b, ntile32); block 256 = 4 waves (rowhalf x fgroup).
// ---------------------------------------------------------------------------
template<int KDIM>
__global__ __launch_bounds__(256) void proj_kernel(
    const unsigned short* __restrict__ A16,   // [8192][KDIM]
    const unsigned short* __restrict__ WT,    // [192][KDIM]
    const unsigned short* __restrict__ WsdT,  // [16][KDIM]
    unsigned short* __restrict__ VT,          // [(b*3+h)*64+f][1024]
    float* __restrict__ st, float* __restrict__ dt)
{
    int b     = blockIdx.x >> 5;
    int nbase = (blockIdx.x & 31) << 5;
    int w = threadIdx.x >> 6, l = threadIdx.x & 63;
    int rh = w & 1, fg = w >> 1;
    int l15 = l & 15, l4 = l >> 4;
    int rowbase = b * 1024 + nbase + rh * 16;

    f32x4 acc[6];
    #pragma unroll
    for (int t = 0; t < 6; ++t) acc[t] = (f32x4)0.f;
    f32x4 sdacc = (f32x4)0.f;

    #pragma unroll
    for (int ks = 0; ks < KDIM / 32; ++ks) {
        int k = ks * 32 + l4 * 8;
        bf16x8 a = *(const bf16x8*)(A16 + (size_t)(rowbase + l15) * KDIM + k);
        #pragma unroll
        for (int t = 0; t < 6; ++t) {
            int n = (fg * 6 + t) * 16 + l15;
            bf16x8 bf = *(const bf16x8*)(WT + (size_t)n * KDIM + k);
            acc[t] = __builtin_amdgcn_mfma_f32_16x16x32_bf16(a, bf, acc[t], 0, 0, 0);
        }
        if (fg == 0) {
            bf16x8 bsd = *(const bf16x8*)(WsdT + (size_t)l15 * KDIM + k);
            sdacc = __builtin_amdgcn_mfma_f32_16x16x32_bf16(a, bsd, sdacc, 0, 0, 0);
        }
    }
    // VT writes: element (row=4*l4+r, col hf)
    #pragma unroll
    for (int t = 0; t < 6; ++t) {
        int hf = (fg * 6 + t) * 16 + l15;
        size_t base = ((size_t)(b * 3 + (hf >> 6)) * 64 + (hf & 63)) * 1024
                      + nbase + rh * 16 + l4 * 4;
        #pragma unroll
        for (int r = 0; r < 4; ++r) VT[base + r] = f2bf(acc[t][r]);
    }
    if (fg == 0 && l15 < 6) {
        int h = l15 >> 1;
        float* dst = (l15 & 1) ? dt : st;
        size_t base = (size_t)(b * 3 + h) * 1024 + nbase + rh * 16 + l4 * 4;
        #pragma unroll
        for (int r = 0; r < 4; ++r) dst[base + r] = sdacc[r];
    }
}

// ---------------------------------------------------------------------------
// Attention: per (b, 32-row tile): for each head, stream j in K=32 chunks,
// build P = exp(leaky(s_i+d_j)) * mask in-register (no max pass; logits are
// bounded), MFMA against VT, track Z, then head-mean + ELU + residual.
// Grid 256; block 256 = 4 waves (rowhalf x fhalf32).
// ---------------------------------------------------------------------------
__global__ __launch_bounds__(256) void attn_kernel(
    const unsigned short* __restrict__ VT,
    const float* __restrict__ st, const float* __restrict__ dt,
    const unsigned long long* __restrict__ maskbits,
    const float* __restrict__ resid,   // may be null
    float* __restrict__ sf_out, unsigned short* __restrict__ sf16_out)
{
    __shared__ unsigned long long lmask64[512];   // 32 rows x 128B
    const unsigned char* lmask = (const unsigned char*)lmask64;

    int b     = blockIdx.x >> 5;
    int ibase = (blockIdx.x & 31) << 5;
    int w = threadIdx.x >> 6, l = threadIdx.x & 63;
    int rh = w & 1, fh = w >> 1;
    int l15 = l & 15, l4 = l >> 4;

    {
        const unsigned long long* src = maskbits + (size_t)ibase * 16;
        lmask64[threadIdx.x]       = src[threadIdx.x];
        lmask64[threadIdx.x + 256] = src[threadIdx.x + 256];
        __syncthreads();
    }

    int rowl = rh * 16 + l15;          // local row for A-frag / mask / s
    f32x4 mean0 = (f32x4)0.f, mean1 = (f32x4)0.f;

    for (int h = 0; h < 3; ++h) {
        int bh = b * 3 + h;
        float sv = st[(size_t)bh * 1024 + ibase + rowl];
        const float* dptr = dt + (size_t)bh * 1024;
        const unsigned short* vbase = VT + ((size_t)bh * 64 + fh * 32) * 1024;
        f32x4 acc0 = (f32x4)0.f, acc1 = (f32x4)0.f;
        float z = 0.f;

        for (int k0 = 0; k0 < 1024; k0 += 32) {
            int kk = k0 + l4 * 8;
            float4 da = *(const float4*)(dptr + kk);
            float4 db = *(const float4*)(dptr + kk + 4);
            unsigned mbyte = lmask[rowl * 128 + (kk >> 3)];
            float dv[8] = {da.x, da.y, da.z, da.w, db.x, db.y, db.z, db.w};
            float p[8];
            #pragma unroll
            for (int j = 0; j < 8; ++j) {
                float t = sv + dv[j];
                t = fmaxf(t, 0.2f * t);                    // leaky_relu
                t = ((mbyte >> j) & 1) ? t : -1e30f;       // mask
                p[j] = fast_exp2(t * LOG2E);
                z += p[j];
            }
            bf16x8 afr;
            #pragma unroll
            for (int j = 0; j < 8; ++j) afr[j] = (short)f2bf(p[j]);
            bf16x8 b0 = *(const bf16x8*)(vbase + (size_t)l15 * 1024 + kk);
            bf16x8 b1 = *(const bf16x8*)(vbase + (size_t)(16 + l15) * 1024 + kk);
            acc0 = __builtin_amdgcn_mfma_f32_16x16x32_bf16(afr, b0, acc0, 0, 0, 0);
            acc1 = __builtin_amdgcn_mfma_f32_16x16x32_bf16(afr, b1, acc1, 0, 0, 0);
        }
        z += __shfl_xor(z, 16);
        z += __shfl_xor(z, 32);                 // lane q holds Z[row q&15]
        #pragma unroll
        for (int r = 0; r < 4; ++r) {
            float zr = __shfl(z, 4 * l4 + r);
            float rcp = 1.0f / ((zr == 0.f) ? 1.f : zr);
            mean0[r] += acc0[r] * rcp;
            mean1[r] += acc1[r] * rcp;
        }
    }

    #pragma unroll
    for (int r = 0; r < 4; ++r) {
        int row = ibase + rh * 16 + 4 * l4 + r;
        size_t ro = ((size_t)b * 1024 + row) * 64;
        #pragma unroll
        for (int t = 0; t < 2; ++t) {
            int f = fh * 32 + t * 16 + l15;
            float o = (t == 0 ? mean0[r] : mean1[r]) * (1.f / 3.f);
            o = (o > 0.f) ? o : (fast_exp2(o * LOG2E) - 1.f);   // ELU
            if (resid) o += resid[ro + f];
            sf_out[ro + f]  = o;
            sf16_out[ro + f] = f2bf(o);
        }
    }
}

// ---------------------------------------------------------------------------
// GRU cell. gi = sf@wi.T, gh = hprev@wh.T (both K=64,N=192 MFMA), gates fp32.
// Grid 256; block 4 waves (rowhalf x colgroup32).
// ---------------------------------------------------------------------------
__global__ __launch_bounds__(256) void gru_kernel(
    const unsigned short* __restrict__ sf16, const unsigned short* __restrict__ hp16,
    const unsigned short* __restrict__ wi16, const unsigned short* __restrict__ wh16,
    const float* __restrict__ bi, const float* __restrict__ bh,
    const float* __restrict__ hprev,
    float* __restrict__ hnew, unsigned short* __restrict__ hn16)
{
    int b     = blockIdx.x >> 5;
    int nbase = (blockIdx.x & 31) << 5;
    int w = threadIdx.x >> 6, l = threadIdx.x & 63;
    int rh = w & 1, g = w >> 1;
    int l15 = l & 15, l4 = l >> 4;
    int rowbase = b * 1024 + nbase + rh * 16;

    f32x4 gi[2][3], gh[2][3];
    #pragma unroll
    for (int t = 0; t < 2; ++t)
        #pragma unroll
        for (int q = 0; q < 3; ++q) { gi[t][q] = (f32x4)0.f; gh[t][q] = (f32x4)0.f; }

    #pragma unroll
    for (int ks = 0; ks < 2; ++ks) {
        int k = ks * 32 + l4 * 8;
        bf16x8 ai = *(const bf16x8*)(sf16 + (size_t)(rowbase + l15) * 64 + k);
        bf16x8 ah = *(const bf16x8*)(hp16 + (size_t)(rowbase + l15) * 64 + k);
        #pragma unroll
        for (int t = 0; t < 2; ++t) {
            #pragma unroll
            for (int q = 0; q < 3; ++q) {
                int n = (q * 4 + g * 2 + t) * 16 + l15;
                bf16x8 bwi = *(const bf16x8*)(wi16 + (size_t)n * 64 + k);
                bf16x8 bwh = *(const bf16x8*)(wh16 + (size_t)n * 64 + k);
                gi[t][q] = __builtin_amdgcn_mfma_f32_16x16x32_bf16(ai, bwi, gi[t][q], 0, 0, 0);
                gh[t][q] = __builtin_amdgcn_mfma_f32_16x16x32_bf16(ah, bwh, gh[t][q], 0, 0, 0);
            }
        }
    }
    #pragma unroll
    for (int t = 0; t < 2; ++t) {
        int c = (g * 2 + t) * 16 + l15;
        float bir = bi[c], biz = bi[64 + c], bin = bi[128 + c];
        float bhr = bh[c], bhz = bh[64 + c], bhn = bh[128 + c];
        #pragma unroll
        for (int r = 0; r < 4; ++r) {
            int row = rowbase + 4 * l4 + r;
            float rr = (gi[t][0][r] + bir) + (gh[t][0][r] + bhr);
            float zz = (gi[t][1][r] + biz) + (gh[t][1][r] + bhz);
            float rg = 1.f / (1.f + fast_exp2(-rr * LOG2E));
            float zg = 1.f / (1.f + fast_exp2(-zz * LOG2E));
            float narg = (gi[t][2][r] + bin) + rg * (gh[t][2][r] + bhn);
            narg = fminf(fmaxf(narg, -15.f), 15.f);
            float e2 = fast_exp2(2.f * narg * LOG2E);
            float ng = (e2 - 1.f) / (e2 + 1.f);
            float hp = hprev[(size_t)row * 64 + c];
            float hv = (1.f - zg) * ng + zg * hp;
            hnew[(size_t)row * 64 + c] = hv;
            hn16[(size_t)row * 64 + c] = f2bf(hv);
        }
    }
}

// ---------------------------------------------------------------------------
// Actor/critic heads. Waves 0,1 = actor, 2,3 = critic.
// ---------------------------------------------------------------------------
__global__ __launch_bounds__(256) void heads_kernel(
    const unsigned short* __restrict__ hn16,
    const unsigned short* __restrict__ Wa1T, const unsigned short* __restrict__ Wc1T,
    const float* __restrict__ ba1, const float* __restrict__ Wa2, const float* __restrict__ ba2,
    const float* __restrict__ bc1, const float* __restrict__ Wc2, const float* __restrict__ bc2,
    float* __restrict__ probs, float* __restrict__ value)
{
    int b     = blockIdx.x >> 5;
    int nbase = (blockIdx.x & 31) << 5;
    int w = threadIdx.x >> 6, l = threadIdx.x & 63;
    int rh = w & 1, path = w >> 1;
    int l15 = l & 15, l4 = l >> 4;
    int rowbase = b * 1024 + nbase + rh * 16;
    const unsigned short* WT = path ? Wc1T : Wa1T;

    f32x4 acc[2] = {(f32x4)0.f, (f32x4)0.f};
    #pragma unroll
    for (int ks = 0; ks < 2; ++ks) {
        int k = ks * 32 + l4 * 8;
        bf16x8 a = *(const bf16x8*)(hn16 + (size_t)(rowbase + l15) * 64 + k);
        #pragma unroll
        for (int t = 0; t < 2; ++t) {
            bf16x8 bf = *(const bf16x8*)(WT + (size_t)(t * 16 + l15) * 64 + k);
            acc[t] = __builtin_amdgcn_mfma_f32_16x16x32_bf16(a, bf, acc[t], 0, 0, 0);
        }
    }
    if (path == 0) {
        float p0[4] = {0.f,0.f,0.f,0.f}, p1[4] = {0.f,0.f,0.f,0.f};
        #pragma unroll
        for (int t = 0; t < 2; ++t) {
            int c = t * 16 + l15;
            float b1 = ba1[c], w20 = Wa2[c * 2], w21 = Wa2[c * 2 + 1];
            #pragma unroll
            for (int r = 0; r < 4; ++r) {
                float v = fmaxf(acc[t][r] + b1, 0.f);
                p0[r] += v * w20; p1[r] += v * w21;
            }
        }
        #pragma unroll
        for (int r = 0; r < 4; ++r) {
            #pragma unroll
            for (int off = 1; off < 16; off <<= 1) {
                p0[r] += __shfl_xor(p0[r], off);
                p1[r] += __shfl_xor(p1[r], off);
            }
            float l0 = p0[r] + ba2[0], l1 = p1[r] + ba2[1];
            float m = fmaxf(l0, l1);
            float e0 = fast_exp2((l0 - m) * LOG2E);
            float e1 = fast_exp2((l1 - m) * LOG2E);
            float s = 1.f / (e0 + e1);
            if (l15 == 0) {
                int row = rowbase + 4 * l4 + r;
                probs[(size_t)row * 2]     = e0 * s;
                probs[(size_t)row * 2 + 1] = e1 * s;
            }
        }
    } else {
        float pv[4] = {0.f,0.f,0.f,0.f};
        #pragma unroll
        for (int t = 0; t < 2; ++t) {
            int c = t * 16 + l15;
            float b1 = bc1[c], w2 = Wc2[c];
            #pragma unroll
            for (int r = 0; r < 4; ++r) {
                float v = fmaxf(acc[t][r] + b1, 0.f);
                pv[r] += v * w2;
            }
        }
        #pragma unroll
        for (int r = 0; r < 4; ++r) {
            #pragma unroll
            for (int off = 1; off < 16; off <<= 1) pv[r] += __shfl_xor(pv[r], off);
            if (l15 == 0) {
                int row = rowbase + 4 * l4 + r;
                value[row] = pv[r] + bc2[0];
            }
        }
    }
}

// ---------------------------------------------------------------------------
extern "C" void kernel_launch(void* const* d_in, const int* in_sizes, int n_in,
                              void* d_out, int out_size, void* d_ws, size_t ws_size,
                              hipStream_t stream)
{
    const float* x      = (const float*)d_in[0];
    const int*   adj    = (const int*)d_in[1];
    const float* h_prev = (const float*)d_in[2];
    const float* W0  = (const float*)d_in[3];
    const float* as0 = (const float*)d_in[4];
    const float* ad0 = (const float*)d_in[5];
    const float* W1  = (const float*)d_in[6];
    const float* as1 = (const float*)d_in[7];
    const float* ad1 = (const float*)d_in[8];
    const float* W2  = (const float*)d_in[9];
    const float* as2 = (const float*)d_in[10];
    const float* ad2 = (const float*)d_in[11];
    const float* gwi = (const float*)d_in[12];
    const float* gwh = (const float*)d_in[13];
    const float* gbi = (const float*)d_in[14];
    const float* gbh = (const float*)d_in[15];
    const float* Wa1 = (const float*)d_in[16];
    const float* ba1 = (const float*)d_in[17];
    const float* Wa2 = (const float*)d_in[18];
    const float* ba2 = (const float*)d_in[19];
    const float* Wc1 = (const float*)d_in[20];
    const float* bc1 = (const float*)d_in[21];
    const float* Wc2 = (const float*)d_in[22];
    const float* bc2 = (const float*)d_in[23];

    float* out   = (float*)d_out;
    float* probs = out;            // (8,1024,2)
    float* value = out + 16384;    // (8,1024,1)
    float* hnew  = out + 24576;    // (8,1024,64)

    char* p = (char*)d_ws;
    auto alloc = [&](size_t bytes) { char* q = p; p += (bytes + 255) & ~(size_t)255; return q; };
    auto* maskb = (unsigned long long*)alloc(16384 * 8);
    float* sfA  = (float*)alloc((size_t)NROWS * 64 * 4);
    float* sfB  = (float*)alloc((size_t)NROWS * 64 * 4);
    auto*  sfA16 = (unsigned short*)alloc((size_t)NROWS * 64 * 2);
    auto*  sfB16 = (unsigned short*)alloc((size_t)NROWS * 64 * 2);
    auto*  xpad  = (unsigned short*)alloc((size_t)NROWS * 32 * 2);
    auto*  hp16  = (unsigned short*)alloc((size_t)NROWS * 64 * 2);
    auto*  hn16  = (unsigned short*)alloc((size_t)NROWS * 64 * 2);
    auto*  VT    = (unsigned short*)alloc((size_t)BB * 3 * 64 * 1024 * 2);
    float* st    = (float*)alloc((size_t)BB * 3 * 1024 * 4);
    float* dt    = (float*)alloc((size_t)BB * 3 * 1024 * 4);
    auto*  W0Tp  = (unsigned short*)alloc(192 * 32 * 2);
    auto*  W1T   = (unsigned short*)alloc(192 * 64 * 2);
    auto*  W2T   = (unsigned short*)alloc(192 * 64 * 2);
    auto*  wi16  = (unsigned short*)alloc(192 * 64 * 2);
    auto*  wh16  = (unsigned short*)alloc(192 * 64 * 2);
    auto*  Wa1T  = (unsigned short*)alloc(32 * 64 * 2);
    auto*  Wc1T  = (unsigned short*)alloc(32 * 64 * 2);
    auto*  Wsd0  = (unsigned short*)alloc(16 * 32 * 2);
    auto*  Wsd1  = (unsigned short*)alloc(16 * 64 * 2);
    auto*  Wsd2  = (unsigned short*)alloc(16 * 64 * 2);
    (void)ws_size; (void)in_sizes; (void)n_in; (void)out_size;

    setup_kernel<<<1024, 256, 0, stream>>>(
        x, adj, h_prev, W0, as0, ad0, W1, as1, ad1, W2, as2, ad2,
        gwi, gwh, Wa1, Wc1,
        maskb, xpad, hp16, W0Tp, W1T, W2T, wi16, wh16, Wa1T, Wc1T,
        Wsd0, Wsd1, Wsd2);

    // Layer 0
    proj_kernel<32><<<256, 256, 0, stream>>>(xpad, W0Tp, Wsd0, VT, st, dt);
    attn_kernel<<<256, 256, 0, stream>>>(VT, st, dt, maskb, nullptr, sfA, sfA16);
    // Layer 1 (residual sfA)
    proj_kernel<64><<<256, 256, 0, stream>>>(sfA16, W1T, Wsd1, VT, st, dt);
    attn_kernel<<<256, 256, 0, stream>>>(VT, st, dt, maskb, sfA, sfB, sfB16);
    // Layer 2 (residual sfB)
    proj_kernel<64><<<256, 256, 0, stream>>>(sfB16, W2T, Wsd2, VT, st, dt);
    attn_kernel<<<256, 256, 0, stream>>>(VT, st, dt, maskb, sfB, sfA, sfA16);
    // GRU + heads
    gru_kernel<<<256, 256, 0, stream>>>(sfA16, hp16, wi16, wh16, gbi, gbh, h_prev, hnew, hn16);
    heads_kernel<<<256, 256, 0, stream>>>(hn16, Wa1T, Wc1T, ba1, Wa2, ba2, bc1, Wc2, bc2, probs, value);
}

// Round 2
// 146.645 us; speedup vs baseline: 1.2264x; 1.2264x over previous
//
#include <hip/hip_runtime.h>
#include <hip/hip_bf16.h>
#include <stdint.h>

// Problem constants
#define NHEADS 3
#define HID 64
#define NN 1024
#define BB 8
#define NROWS 8192   // B*N

using bf16x8 = __attribute__((ext_vector_type(8))) short;
using f32x4  = __attribute__((ext_vector_type(4))) float;

__device__ __forceinline__ unsigned short f2bf(float f) {
    unsigned u = __float_as_uint(f);
    u += 0x7fff + ((u >> 16) & 1);          // RNE
    return (unsigned short)(u >> 16);
}
__device__ __forceinline__ float fast_exp2(float x) {
    return __builtin_amdgcn_exp2f(x);
}
#define LOG2E 1.44269504f

// ---------------------------------------------------------------------------
// Setup: pack adjacency bits, bf16-convert/transpose weights, pad x, precompute
// Wsd = W @ blockdiag(a_src|a_dst) so s,d come out of the proj MFMA directly.
// Grid: 1024 blocks x 256 threads.
// ---------------------------------------------------------------------------
__global__ __launch_bounds__(256) void setup_kernel(
    const float* __restrict__ x, const int* __restrict__ adj, const float* __restrict__ h_prev,
    const float* __restrict__ W0, const float* __restrict__ as0, const float* __restrict__ ad0,
    const float* __restrict__ W1, const float* __restrict__ as1, const float* __restrict__ ad1,
    const float* __restrict__ W2, const float* __restrict__ as2, const float* __restrict__ ad2,
    const float* __restrict__ gwi, const float* __restrict__ gwh,
    const float* __restrict__ Wa1, const float* __restrict__ Wc1,
    unsigned long long* __restrict__ maskbits, unsigned short* __restrict__ xpad,
    unsigned short* __restrict__ hp16,
    unsigned short* __restrict__ W0Tp, unsigned short* __restrict__ W1T, unsigned short* __restrict__ W2T,
    unsigned short* __restrict__ wi16, unsigned short* __restrict__ wh16,
    unsigned short* __restrict__ Wa1T, unsigned short* __restrict__ Wc1T,
    unsigned short* __restrict__ Wsd0, unsigned short* __restrict__ Wsd1, unsigned short* __restrict__ Wsd2)
{
    int tid  = blockIdx.x * 256 + threadIdx.x;   // 0 .. 262143
    int lane = threadIdx.x & 63;
    int wv   = tid >> 6;                         // global wave id 0..4095

    // 1) adjacency -> bitmask: 16384 u64 words, 4 per wave
    #pragma unroll
    for (int i = 0; i < 4; ++i) {
        int w   = wv * 4 + i;                    // word index
        int row = w >> 4, wc = w & 15;
        int j   = wc * 64 + lane;
        unsigned long long m = __ballot(adj[row * 1024 + j] > 0);
        if (lane == 0) maskbits[w] = m;
    }
    // 2) x padded to [8192][32] bf16 (k<3 real)
    {
        int n = tid >> 5, k = tid & 31;
        xpad[tid] = (k < 3) ? f2bf(x[n * 3 + k]) : (unsigned short)0;
    }
    // 3) h_prev bf16 copy (524288 els, 2/thread)
    hp16[tid]          = f2bf(h_prev[tid]);
    hp16[tid + 262144] = f2bf(h_prev[tid + 262144]);
    // 4) W1T/W2T [192][64] transposed; gru wi/wh already [n][k], just convert
    if (tid < 12288) {
        int n = tid >> 6, k = tid & 63;
        W1T[tid]  = f2bf(W1[k * 192 + n]);
        W2T[tid]  = f2bf(W2[k * 192 + n]);
        wi16[tid] = f2bf(gwi[tid]);
        wh16[tid] = f2bf(gwh[tid]);
    }
    // 5) W0T padded [192][32]
    if (tid < 6144) {
        int n = tid >> 5, k = tid & 31;
        W0Tp[tid] = (k < 3) ? f2bf(W0[k * 192 + n]) : (unsigned short)0;
    }
    // 6) Wa1T/Wc1T [32][64]
    if (tid < 2048) {
        int n = tid >> 6, k = tid & 63;
        Wa1T[tid] = f2bf(Wa1[k * 32 + n]);
        Wc1T[tid] = f2bf(Wc1[k * 32 + n]);
    }
    // 7) Wsd: [16 cols][K] bf16; col c = 2h+isdst -> sum_f W[k][h*64+f]*a[h][f]
    if (tid < 16 * 32) {   // layer 0, K=32 (k<3 real)
        int c = tid >> 5, k = tid & 31;
        float v = 0.f;
        if (c < 6 && k < 3) {
            int h = c >> 1; const float* a = (c & 1) ? ad0 : as0;
            for (int f = 0; f < 64; ++f) v += W0[k * 192 + h * 64 + f] * a[h * 64 + f];
        }
        Wsd0[tid] = f2bf(v);
    }
    if (tid < 16 * 64) {   // layers 1,2, K=64
        int c = tid >> 6, k = tid & 63;
        float v1 = 0.f, v2 = 0.f;
        if (c < 6) {
            int h = c >> 1;
            const float* a1 = (c & 1) ? ad1 : as1;
            const float* a2 = (c & 1) ? ad2 : as2;
            for (int f = 0; f < 64; ++f) {
                v1 += W1[k * 192 + h * 64 + f] * a1[h * 64 + f];
                v2 += W2[k * 192 + h * 64 + f] * a2[h * 64 + f];
            }
        }
        Wsd1[tid] = f2bf(v1);
        Wsd2[tid] = f2bf(v2);
    }
}

// ---------------------------------------------------------------------------
// Projection: Wh = A(32xK) @ W(Kx192), plus s/d via the Wsd tile.
// Writes VT bf16 [b][h][f][n] (transposed for attn B-frags), st/dt f32 [b][h][n].
// Grid 256 = (b, ntile32); block 256 = 4 waves (rowhalf x fgroup).
// ---------------------------------------------------------------------------
template<int KDIM>
__global__ __launch_bounds__(256) void proj_kernel(
    const unsigned short* __restrict__ A16,   // [8192][KDIM]
    const unsigned short* __restrict__ WT,    // [192][KDIM]
    const unsigned short* __restrict__ WsdT,  // [16][KDIM]
    unsigned short* __restrict__ VT,          // [(b*3+h)*64+f][1024]
    float* __restrict__ st, float* __restrict__ dt)
{
    int b     = blockIdx.x >> 5;
    int nbase = (blockIdx.x & 31) << 5;
    int w = threadIdx.x >> 6, l = threadIdx.x & 63;
    int rh = w & 1, fg = w >> 1;
    int l15 = l & 15, l4 = l >> 4;
    int rowbase = b * 1024 + nbase + rh * 16;

    f32x4 acc[6];
    #pragma unroll
    for (int t = 0; t < 6; ++t) acc[t] = (f32x4)0.f;
    f32x4 sdacc = (f32x4)0.f;

    #pragma unroll
    for (int ks = 0; ks < KDIM / 32; ++ks) {
        int k = ks * 32 + l4 * 8;
        bf16x8 a = *(const bf16x8*)(A16 + (size_t)(rowbase + l15) * KDIM + k);
        #pragma unroll
        for (int t = 0; t < 6; ++t) {
            int n = (fg * 6 + t) * 16 + l15;
            bf16x8 bf = *(const bf16x8*)(WT + (size_t)n * KDIM + k);
            acc[t] = __builtin_amdgcn_mfma_f32_16x16x32_bf16(a, bf, acc[t], 0, 0, 0);
        }
        if (fg == 0) {
            bf16x8 bsd = *(const bf16x8*)(WsdT + (size_t)l15 * KDIM + k);
            sdacc = __builtin_amdgcn_mfma_f32_16x16x32_bf16(a, bsd, sdacc, 0, 0, 0);
        }
    }
    // VT writes: element (row=4*l4+r, col hf)
    #pragma unroll
    for (int t = 0; t < 6; ++t) {
        int hf = (fg * 6 + t) * 16 + l15;
        size_t base = ((size_t)(b * 3 + (hf >> 6)) * 64 + (hf & 63)) * 1024
                      + nbase + rh * 16 + l4 * 4;
        #pragma unroll
        for (int r = 0; r < 4; ++r) VT[base + r] = f2bf(acc[t][r]);
    }
    if (fg == 0 && l15 < 6) {
        int h = l15 >> 1;
        float* dst = (l15 & 1) ? dt : st;
        size_t base = (size_t)(b * 3 + h) * 1024 + nbase + rh * 16 + l4 * 4;
        #pragma unroll
        for (int r = 0; r < 4; ++r) dst[base + r] = sdacc[r];
    }
}

// ---------------------------------------------------------------------------
// Attention (per-head): grid 768 = (b*3+h)*32 + tile. Each block: 32 query
// rows x 1024 j for ONE head. P built in-register (no softmax max pass;
// logits bounded), MFMA vs VT, per-row Z tracked, normalized write to hacc.
// Mask staged in LDS as u32 words with stride 33 (conflict-free).
// Block 256 = 4 waves (rowhalf x fhalf32).
// ---------------------------------------------------------------------------
__global__ __launch_bounds__(256) void attn_head_kernel(
    const unsigned short* __restrict__ VT,
    const float* __restrict__ st, const float* __restrict__ dt,
    const unsigned int* __restrict__ maskw,   // [1024 rows][32 u32 words]
    float* __restrict__ hacc)                 // [(b*3+h)][1024][64]
{
    __shared__ unsigned int lmask[32 * 33];

    int bh    = blockIdx.x >> 5;              // b*3 + h
    int ibase = (blockIdx.x & 31) << 5;
    int w = threadIdx.x >> 6, l = threadIdx.x & 63;
    int rh = w & 1, fh = w >> 1;
    int l15 = l & 15, l4 = l >> 4;

    // stage mask words, padded stride 33
    #pragma unroll
    for (int i = 0; i < 4; ++i) {
        int idx = threadIdx.x + i * 256;      // 0..1023
        int row = idx >> 5, wd = idx & 31;
        lmask[row * 33 + wd] = maskw[(size_t)(ibase + row) * 32 + wd];
    }
    __syncthreads();

    int rowl = rh * 16 + l15;
    float sv = st[(size_t)bh * 1024 + ibase + rowl];
    const float* dptr = dt + (size_t)bh * 1024;
    const unsigned short* vbase = VT + ((size_t)bh * 64 + fh * 32) * 1024;

    f32x4 acc0 = (f32x4)0.f, acc1 = (f32x4)0.f;
    float z = 0.f;

    #pragma unroll 2
    for (int k0 = 0; k0 < 1024; k0 += 32) {
        int kk = k0 + l4 * 8;
        float4 da = *(const float4*)(dptr + kk);
        float4 db = *(const float4*)(dptr + kk + 4);
        unsigned mword = lmask[rowl * 33 + (k0 >> 5)];
        unsigned mbyte = (mword >> (l4 * 8)) & 0xffu;
        float dv[8] = {da.x, da.y, da.z, da.w, db.x, db.y, db.z, db.w};
        float p[8];
        #pragma unroll
        for (int j = 0; j < 8; ++j) {
            float t = sv + dv[j];
            t = fmaxf(t, 0.2f * t);                    // leaky_relu
            t = ((mbyte >> j) & 1) ? t : -1e30f;       // mask
            p[j] = fast_exp2(t * LOG2E);
            z += p[j];
        }
        bf16x8 afr;
        #pragma unroll
        for (int j = 0; j < 8; ++j) afr[j] = (short)f2bf(p[j]);
        bf16x8 b0 = *(const bf16x8*)(vbase + (size_t)l15 * 1024 + kk);
        bf16x8 b1 = *(const bf16x8*)(vbase + (size_t)(16 + l15) * 1024 + kk);
        acc0 = __builtin_amdgcn_mfma_f32_16x16x32_bf16(afr, b0, acc0, 0, 0, 0);
        acc1 = __builtin_amdgcn_mfma_f32_16x16x32_bf16(afr, b1, acc1, 0, 0, 0);
    }
    z += __shfl_xor(z, 16);
    z += __shfl_xor(z, 32);                   // lane q holds Z[row q&15]

    #pragma unroll
    for (int r = 0; r < 4; ++r) {
        float zr  = __shfl(z, 4 * l4 + r);
        float rcp = 1.0f / ((zr == 0.f) ? 1.f : zr);
        int row = ibase + rh * 16 + 4 * l4 + r;
        size_t ro = ((size_t)bh * 1024 + row) * 64;
        hacc[ro + fh * 32 + l15]      = acc0[r] * rcp;
        hacc[ro + fh * 32 + 16 + l15] = acc1[r] * rcp;
    }
}

// ---------------------------------------------------------------------------
// Combine heads: mean over 3 heads, ELU, +residual; write f32 + bf16.
// Grid 512 x 256; one float4 per thread.
// ---------------------------------------------------------------------------
__global__ __launch_bounds__(256) void combine_kernel(
    const float* __restrict__ hacc, const float* __restrict__ resid,
    float* __restrict__ sf_out, unsigned short* __restrict__ sf16_out)
{
    int idx = blockIdx.x * 256 + threadIdx.x;   // 0..131071
    int row = idx >> 4;                         // b*1024 + n
    int fq  = idx & 15;
    int b   = row >> 10, n = row & 1023;
    size_t hbase = (((size_t)b * 3) * 1024 + n) * 64 + fq * 4;

    float4 v0 = *(const float4*)(hacc + hbase);
    float4 v1 = *(const float4*)(hacc + hbase + 65536);
    float4 v2 = *(const float4*)(hacc + hbase + 131072);
    float o[4] = {v0.x + v1.x + v2.x, v0.y + v1.y + v2.y,
                  v0.z + v1.z + v2.z, v0.w + v1.w + v2.w};
    size_t ro = (size_t)row * 64 + fq * 4;
    float4 rs = resid ? *(const float4*)(resid + ro) : make_float4(0.f, 0.f, 0.f, 0.f);
    float rr[4] = {rs.x, rs.y, rs.z, rs.w};
    float out[4];
    short4 o16;
    #pragma unroll
    for (int j = 0; j < 4; ++j) {
        float v = o[j] * (1.f / 3.f);
        v = (v > 0.f) ? v : (fast_exp2(v * LOG2E) - 1.f);   // ELU
        v += rr[j];
        out[j] = v;
        ((unsigned short*)&o16)[j] = f2bf(v);
    }
    *(float4*)(sf_out + ro) = make_float4(out[0], out[1], out[2], out[3]);
    *(short4*)(sf16_out + ro) = o16;
}

// ---------------------------------------------------------------------------
// GRU cell. gi = sf@wi.T, gh = hprev@wh.T (both K=64,N=192 MFMA), gates fp32.
// Grid 256; block 4 waves (rowhalf x colgroup32).
// ---------------------------------------------------------------------------
__global__ __launch_bounds__(256) void gru_kernel(
    const unsigned short* __restrict__ sf16, const unsigned short* __restrict__ hp16,
    const unsigned short* __restrict__ wi16, const unsigned short* __restrict__ wh16,
    const float* __restrict__ bi, const float* __restrict__ bh,
    const float* __restrict__ hprev,
    float* __restrict__ hnew, unsigned short* __restrict__ hn16)
{
    int b     = blockIdx.x >> 5;
    int nbase = (blockIdx.x & 31) << 5;
    int w = threadIdx.x >> 6, l = threadIdx.x & 63;
    int rh = w & 1, g = w >> 1;
    int l15 = l & 15, l4 = l >> 4;
    int rowbase = b * 1024 + nbase + rh * 16;

    f32x4 gi[2][3], gh[2][3];
    #pragma unroll
    for (int t = 0; t < 2; ++t)
        #pragma unroll
        for (int q = 0; q < 3; ++q) { gi[t][q] = (f32x4)0.f; gh[t][q] = (f32x4)0.f; }

    #pragma unroll
    for (int ks = 0; ks < 2; ++ks) {
        int k = ks * 32 + l4 * 8;
        bf16x8 ai = *(const bf16x8*)(sf16 + (size_t)(rowbase + l15) * 64 + k);
        bf16x8 ah = *(const bf16x8*)(hp16 + (size_t)(rowbase + l15) * 64 + k);
        #pragma unroll
        for (int t = 0; t < 2; ++t) {
            #pragma unroll
            for (int q = 0; q < 3; ++q) {
                int n = (q * 4 + g * 2 + t) * 16 + l15;
                bf16x8 bwi = *(const bf16x8*)(wi16 + (size_t)n * 64 + k);
                bf16x8 bwh = *(const bf16x8*)(wh16 + (size_t)n * 64 + k);
                gi[t][q] = __builtin_amdgcn_mfma_f32_16x16x32_bf16(ai, bwi, gi[t][q], 0, 0, 0);
                gh[t][q] = __builtin_amdgcn_mfma_f32_16x16x32_bf16(ah, bwh, gh[t][q], 0, 0, 0);
            }
        }
    }
    #pragma unroll
    for (int t = 0; t < 2; ++t) {
        int c = (g * 2 + t) * 16 + l15;
        float bir = bi[c], biz = bi[64 + c], bin = bi[128 + c];
        float bhr = bh[c], bhz = bh[64 + c], bhn = bh[128 + c];
        #pragma unroll
        for (int r = 0; r < 4; ++r) {
            int row = rowbase + 4 * l4 + r;
            float rr = (gi[t][0][r] + bir) + (gh[t][0][r] + bhr);
            float zz = (gi[t][1][r] + biz) + (gh[t][1][r] + bhz);
            float rg = 1.f / (1.f + fast_exp2(-rr * LOG2E));
            float zg = 1.f / (1.f + fast_exp2(-zz * LOG2E));
            float narg = (gi[t][2][r] + bin) + rg * (gh[t][2][r] + bhn);
            narg = fminf(fmaxf(narg, -15.f), 15.f);
            float e2 = fast_exp2(2.f * narg * LOG2E);
            float ng = (e2 - 1.f) / (e2 + 1.f);
            float hp = hprev[(size_t)row * 64 + c];
            float hv = (1.f - zg) * ng + zg * hp;
            hnew[(size_t)row * 64 + c] = hv;
            hn16[(size_t)row * 64 + c] = f2bf(hv);
        }
    }
}

// ---------------------------------------------------------------------------
// Actor/critic heads. Waves 0,1 = actor, 2,3 = critic.
// ---------------------------------------------------------------------------
__global__ __launch_bounds__(256) void heads_kernel(
    const unsigned short* __restrict__ hn16,
    const unsigned short* __restrict__ Wa1T, const unsigned short* __restrict__ Wc1T,
    const float* __restrict__ ba1, const float* __restrict__ Wa2, const float* __restrict__ ba2,
    const float* __restrict__ bc1, const float* __restrict__ Wc2, const float* __restrict__ bc2,
    float* __restrict__ probs, float* __restrict__ value)
{
    int b     = blockIdx.x >> 5;
    int nbase = (blockIdx.x & 31) << 5;
    int w = threadIdx.x >> 6, l = threadIdx.x & 63;
    int rh = w & 1, path = w >> 1;
    int l15 = l & 15, l4 = l >> 4;
    int rowbase = b * 1024 + nbase + rh * 16;
    const unsigned short* WT = path ? Wc1T : Wa1T;

    f32x4 acc[2] = {(f32x4)0.f, (f32x4)0.f};
    #pragma unroll
    for (int ks = 0; ks < 2; ++ks) {
        int k = ks * 32 + l4 * 8;
        bf16x8 a = *(const bf16x8*)(hn16 + (size_t)(rowbase + l15) * 64 + k);
        #pragma unroll
        for (int t = 0; t < 2; ++t) {
            bf16x8 bf = *(const bf16x8*)(WT + (size_t)(t * 16 + l15) * 64 + k);
            acc[t] = __builtin_amdgcn_mfma_f32_16x16x32_bf16(a, bf, acc[t], 0, 0, 0);
        }
    }
    if (path == 0) {
        float p0[4] = {0.f,0.f,0.f,0.f}, p1[4] = {0.f,0.f,0.f,0.f};
        #pragma unroll
        for (int t = 0; t < 2; ++t) {
            int c = t * 16 + l15;
            float b1 = ba1[c], w20 = Wa2[c * 2], w21 = Wa2[c * 2 + 1];
            #pragma unroll
            for (int r = 0; r < 4; ++r) {
                float v = fmaxf(acc[t][r] + b1, 0.f);
                p0[r] += v * w20; p1[r] += v * w21;
            }
        }
        #pragma unroll
        for (int r = 0; r < 4; ++r) {
            #pragma unroll
            for (int off = 1; off < 16; off <<= 1) {
                p0[r] += __shfl_xor(p0[r], off);
                p1[r] += __shfl_xor(p1[r], off);
            }
            float l0 = p0[r] + ba2[0], l1 = p1[r] + ba2[1];
            float m = fmaxf(l0, l1);
            float e0 = fast_exp2((l0 - m) * LOG2E);
            float e1 = fast_exp2((l1 - m) * LOG2E);
            float s = 1.f / (e0 + e1);
            if (l15 == 0) {
                int row = rowbase + 4 * l4 + r;
                probs[(size_t)row * 2]     = e0 * s;
                probs[(size_t)row * 2 + 1] = e1 * s;
            }
        }
    } else {
        float pv[4] = {0.f,0.f,0.f,0.f};
        #pragma unroll
        for (int t = 0; t < 2; ++t) {
            int c = t * 16 + l15;
            float b1 = bc1[c], w2 = Wc2[c];
            #pragma unroll
            for (int r = 0; r < 4; ++r) {
                float v = fmaxf(acc[t][r] + b1, 0.f);
                pv[r] += v * w2;
            }
        }
        #pragma unroll
        for (int r = 0; r < 4; ++r) {
            #pragma unroll
            for (int off = 1; off < 16; off <<= 1) pv[r] += __shfl_xor(pv[r], off);
            if (l15 == 0) {
                int row = rowbase + 4 * l4 + r;
                value[row] = pv[r] + bc2[0];
            }
        }
    }
}

// ---------------------------------------------------------------------------
extern "C" void kernel_launch(void* const* d_in, const int* in_sizes, int n_in,
                              void* d_out, int out_size, void* d_ws, size_t ws_size,
                              hipStream_t stream)
{
    const float* x      = (const float*)d_in[0];
    const int*   adj    = (const int*)d_in[1];
    const float* h_prev = (const float*)d_in[2];
    const float* W0  = (const float*)d_in[3];
    const float* as0 = (const float*)d_in[4];
    const float* ad0 = (const float*)d_in[5];
    const float* W1  = (const float*)d_in[6];
    const float* as1 = (const float*)d_in[7];
    const float* ad1 = (const float*)d_in[8];
    const float* W2  = (const float*)d_in[9];
    const float* as2 = (const float*)d_in[10];
    const float* ad2 = (const float*)d_in[11];
    const float* gwi = (const float*)d_in[12];
    const float* gwh = (const float*)d_in[13];
    const float* gbi = (const float*)d_in[14];
    const float* gbh = (const float*)d_in[15];
    const float* Wa1 = (const float*)d_in[16];
    const float* ba1 = (const float*)d_in[17];
    const float* Wa2 = (const float*)d_in[18];
    const float* ba2 = (const float*)d_in[19];
    const float* Wc1 = (const float*)d_in[20];
    const float* bc1 = (const float*)d_in[21];
    const float* Wc2 = (const float*)d_in[22];
    const float* bc2 = (const float*)d_in[23];

    float* out   = (float*)d_out;
    float* probs = out;            // (8,1024,2)
    float* value = out + 16384;    // (8,1024,1)
    float* hnew  = out + 24576;    // (8,1024,64)

    char* p = (char*)d_ws;
    auto alloc = [&](size_t bytes) { char* q = p; p += (bytes + 255) & ~(size_t)255; return q; };
    auto* maskb = (unsigned long long*)alloc(16384 * 8);
    float* sfA  = (float*)alloc((size_t)NROWS * 64 * 4);
    float* sfB  = (float*)alloc((size_t)NROWS * 64 * 4);
    auto*  sfA16 = (unsigned short*)alloc((size_t)NROWS * 64 * 2);
    auto*  sfB16 = (unsigned short*)alloc((size_t)NROWS * 64 * 2);
    auto*  xpad  = (unsigned short*)alloc((size_t)NROWS * 32 * 2);
    auto*  hp16  = (unsigned short*)alloc((size_t)NROWS * 64 * 2);
    auto*  hn16  = (unsigned short*)alloc((size_t)NROWS * 64 * 2);
    auto*  VT    = (unsigned short*)alloc((size_t)BB * 3 * 64 * 1024 * 2);
    float* st    = (float*)alloc((size_t)BB * 3 * 1024 * 4);
    float* dt    = (float*)alloc((size_t)BB * 3 * 1024 * 4);
    float* hacc  = (float*)alloc((size_t)BB * 3 * 1024 * 64 * 4);
    auto*  W0Tp  = (unsigned short*)alloc(192 * 32 * 2);
    auto*  W1T   = (unsigned short*)alloc(192 * 64 * 2);
    auto*  W2T   = (unsigned short*)alloc(192 * 64 * 2);
    auto*  wi16  = (unsigned short*)alloc(192 * 64 * 2);
    auto*  wh16  = (unsigned short*)alloc(192 * 64 * 2);
    auto*  Wa1T  = (unsigned short*)alloc(32 * 64 * 2);
    auto*  Wc1T  = (unsigned short*)alloc(32 * 64 * 2);
    auto*  Wsd0  = (unsigned short*)alloc(16 * 32 * 2);
    auto*  Wsd1  = (unsigned short*)alloc(16 * 64 * 2);
    auto*  Wsd2  = (unsigned short*)alloc(16 * 64 * 2);
    (void)ws_size; (void)in_sizes; (void)n_in; (void)out_size;

    const unsigned int* maskw = (const unsigned int*)maskb;

    setup_kernel<<<1024, 256, 0, stream>>>(
        x, adj, h_prev, W0, as0, ad0, W1, as1, ad1, W2, as2, ad2,
        gwi, gwh, Wa1, Wc1,
        maskb, xpad, hp16, W0Tp, W1T, W2T, wi16, wh16, Wa1T, Wc1T,
        Wsd0, Wsd1, Wsd2);

    // Layer 0
    proj_kernel<32><<<256, 256, 0, stream>>>(xpad, W0Tp, Wsd0, VT, st, dt);
    attn_head_kernel<<<768, 256, 0, stream>>>(VT, st, dt, maskw, hacc);
    combine_kernel<<<512, 256, 0, stream>>>(hacc, nullptr, sfA, sfA16);
    // Layer 1 (residual sfA)
    proj_kernel<64><<<256, 256, 0, stream>>>(sfA16, W1T, Wsd1, VT, st, dt);
    attn_head_kernel<<<768, 256, 0, stream>>>(VT, st, dt, maskw, hacc);
    combine_kernel<<<512, 256, 0, stream>>>(hacc, sfA, sfB, sfB16);
    // Layer 2 (residual sfB)
    proj_kernel<64><<<256, 256, 0, stream>>>(sfB16, W2T, Wsd2, VT, st, dt);
    attn_head_kernel<<<768, 256, 0, stream>>>(VT, st, dt, maskw, hacc);
    combine_kernel<<<512, 256, 0, stream>>>(hacc, sfB, sfA, sfA16);
    // GRU + heads
    gru_kernel<<<256, 256, 0, stream>>>(sfA16, hp16, wi16, wh16, gbi, gbh, h_prev, hnew, hn16);
    heads_kernel<<<256, 256, 0, stream>>>(hn16, Wa1T, Wc1T, ba1, Wa2, ba2, bc1, Wc2, bc2, probs, value);
}

// Round 3
// 111.026 us; speedup vs baseline: 1.6198x; 1.3208x over previous
//
#include <hip/hip_runtime.h>
#include <hip/hip_bf16.h>
#include <stdint.h>

#define NHEADS 3
#define HID 64
#define NN 1024
#define BB 8
#define NROWS 8192   // B*N

using bf16x8 = __attribute__((ext_vector_type(8))) short;
using f32x4  = __attribute__((ext_vector_type(4))) float;

__device__ __forceinline__ unsigned short f2bf(float f) {
    unsigned u = __float_as_uint(f);
    u += 0x7fff + ((u >> 16) & 1);          // RNE
    return (unsigned short)(u >> 16);
}
__device__ __forceinline__ unsigned cvt_pk_bf16(float lo, float hi) {
    unsigned r;
    asm volatile("v_cvt_pk_bf16_f32 %0, %1, %2" : "=v"(r) : "v"(lo), "v"(hi));
    return r;
}
__device__ __forceinline__ float fast_exp2(float x) {
    return __builtin_amdgcn_exp2f(x);
}
#define LOG2E 1.44269504f

// ---------------------------------------------------------------------------
// Setup: pack adjacency bits, bf16 weights, pad x, precompute Wsd.
// ---------------------------------------------------------------------------
__global__ __launch_bounds__(256) void setup_kernel(
    const float* __restrict__ x, const int* __restrict__ adj, const float* __restrict__ h_prev,
    const float* __restrict__ W0, const float* __restrict__ as0, const float* __restrict__ ad0,
    const float* __restrict__ W1, const float* __restrict__ as1, const float* __restrict__ ad1,
    const float* __restrict__ W2, const float* __restrict__ as2, const float* __restrict__ ad2,
    const float* __restrict__ gwi, const float* __restrict__ gwh,
    const float* __restrict__ Wa1, const float* __restrict__ Wc1,
    unsigned long long* __restrict__ maskbits, unsigned short* __restrict__ xpad,
    unsigned short* __restrict__ hp16,
    unsigned short* __restrict__ W0Tp, unsigned short* __restrict__ W1T, unsigned short* __restrict__ W2T,
    unsigned short* __restrict__ wi16, unsigned short* __restrict__ wh16,
    unsigned short* __restrict__ Wa1T, unsigned short* __restrict__ Wc1T,
    unsigned short* __restrict__ Wsd0, unsigned short* __restrict__ Wsd1, unsigned short* __restrict__ Wsd2)
{
    int tid  = blockIdx.x * 256 + threadIdx.x;   // 0 .. 262143
    int lane = threadIdx.x & 63;
    int wv   = tid >> 6;

    #pragma unroll
    for (int i = 0; i < 4; ++i) {
        int w   = wv * 4 + i;
        int row = w >> 4, wc = w & 15;
        int j   = wc * 64 + lane;
        unsigned long long m = __ballot(adj[row * 1024 + j] > 0);
        if (lane == 0) maskbits[w] = m;
    }
    {
        int n = tid >> 5, k = tid & 31;
        xpad[tid] = (k < 3) ? f2bf(x[n * 3 + k]) : (unsigned short)0;
    }
    hp16[tid]          = f2bf(h_prev[tid]);
    hp16[tid + 262144] = f2bf(h_prev[tid + 262144]);
    if (tid < 12288) {
        int n = tid >> 6, k = tid & 63;
        W1T[tid]  = f2bf(W1[k * 192 + n]);
        W2T[tid]  = f2bf(W2[k * 192 + n]);
        wi16[tid] = f2bf(gwi[tid]);
        wh16[tid] = f2bf(gwh[tid]);
    }
    if (tid < 6144) {
        int n = tid >> 5, k = tid & 31;
        W0Tp[tid] = (k < 3) ? f2bf(W0[k * 192 + n]) : (unsigned short)0;
    }
    if (tid < 2048) {
        int n = tid >> 6, k = tid & 63;
        Wa1T[tid] = f2bf(Wa1[k * 32 + n]);
        Wc1T[tid] = f2bf(Wc1[k * 32 + n]);
    }
    if (tid < 16 * 32) {
        int c = tid >> 5, k = tid & 31;
        float v = 0.f;
        if (c < 6 && k < 3) {
            int h = c >> 1; const float* a = (c & 1) ? ad0 : as0;
            for (int f = 0; f < 64; ++f) v += W0[k * 192 + h * 64 + f] * a[h * 64 + f];
        }
        Wsd0[tid] = f2bf(v);
    }
    if (tid < 16 * 64) {
        int c = tid >> 6, k = tid & 63;
        float v1 = 0.f, v2 = 0.f;
        if (c < 6) {
            int h = c >> 1;
            const float* a1 = (c & 1) ? ad1 : as1;
            const float* a2 = (c & 1) ? ad2 : as2;
            for (int f = 0; f < 64; ++f) {
                v1 += W1[k * 192 + h * 64 + f] * a1[h * 64 + f];
                v2 += W2[k * 192 + h * 64 + f] * a2[h * 64 + f];
            }
        }
        Wsd1[tid] = f2bf(v1);
        Wsd2[tid] = f2bf(v2);
    }
}

// ---------------------------------------------------------------------------
// Projection. MODE 0: A from bf16 buffer (layer0). MODE 1: A = ELU(mean(hacc)),
// writes rsum = that. MODE 2: A = rsum + ELU(mean(hacc)), writes rsum = A.
// Grid 512 = (b, ntile16); block 256 = 4 waves, wave = fg (3 f-frags each).
// Writes VT bf16 [(b*3+h)*64+f][1024], st/dt f32 [b*3+h][1024].
// ---------------------------------------------------------------------------
template<int KDIM, int MODE>
__global__ __launch_bounds__(256) void proj_kernel(
    const unsigned short* __restrict__ A16,
    const float* __restrict__ haccp,          // [b][1024][192]
    float* __restrict__ rsum,                 // [8192][64]
    const unsigned short* __restrict__ WT,    // [192][KDIM]
    const unsigned short* __restrict__ WsdT,  // [16][KDIM]
    unsigned short* __restrict__ VT,
    float* __restrict__ st, float* __restrict__ dt)
{
    int b     = blockIdx.x >> 6;
    int nbase = (blockIdx.x & 63) << 4;
    int fg = threadIdx.x >> 6, l = threadIdx.x & 63;
    int l15 = l & 15, l4 = l >> 4;
    int row = b * 1024 + nbase + l15;
    constexpr int NK = KDIM / 32;

    bf16x8 afr[NK];
    if constexpr (MODE == 0) {
        #pragma unroll
        for (int ks = 0; ks < NK; ++ks)
            afr[ks] = *(const bf16x8*)(A16 + (size_t)row * KDIM + ks * 32 + l4 * 8);
    } else {
        float sf[2][8];
        #pragma unroll
        for (int ks = 0; ks < 2; ++ks) {
            int fb = ks * 32 + l4 * 8;
            const float* hp = haccp + (size_t)row * 192 + fb;
            float4 a0 = *(const float4*)(hp);       float4 a1 = *(const float4*)(hp + 4);
            float4 c0 = *(const float4*)(hp + 64);  float4 c1 = *(const float4*)(hp + 68);
            float4 e0 = *(const float4*)(hp + 128); float4 e1 = *(const float4*)(hp + 132);
            float m[8] = {a0.x + c0.x + e0.x, a0.y + c0.y + e0.y, a0.z + c0.z + e0.z, a0.w + c0.w + e0.w,
                          a1.x + c1.x + e1.x, a1.y + c1.y + e1.y, a1.z + c1.z + e1.z, a1.w + c1.w + e1.w};
            float r[8] = {0.f,0.f,0.f,0.f,0.f,0.f,0.f,0.f};
            if constexpr (MODE == 2) {
                const float* rp = rsum + (size_t)row * 64 + fb;
                float4 r0 = *(const float4*)(rp); float4 r1 = *(const float4*)(rp + 4);
                r[0]=r0.x; r[1]=r0.y; r[2]=r0.z; r[3]=r0.w;
                r[4]=r1.x; r[5]=r1.y; r[6]=r1.z; r[7]=r1.w;
            }
            #pragma unroll
            for (int j = 0; j < 8; ++j) {
                float v = m[j] * (1.f / 3.f);
                v = (v > 0.f) ? v : (fast_exp2(v * LOG2E) - 1.f);   // ELU
                sf[ks][j] = v + r[j];
            }
        }
        __syncthreads();           // all rsum reads done before any write
        if (fg == 0) {
            #pragma unroll
            for (int ks = 0; ks < 2; ++ks) {
                float* rp = rsum + (size_t)row * 64 + ks * 32 + l4 * 8;
                *(float4*)(rp)     = make_float4(sf[ks][0], sf[ks][1], sf[ks][2], sf[ks][3]);
                *(float4*)(rp + 4) = make_float4(sf[ks][4], sf[ks][5], sf[ks][6], sf[ks][7]);
            }
        }
        #pragma unroll
        for (int ks = 0; ks < 2; ++ks) {
            union { unsigned u[4]; bf16x8 v; } uu;
            #pragma unroll
            for (int jj = 0; jj < 4; ++jj)
                uu.u[jj] = cvt_pk_bf16(sf[ks][2 * jj], sf[ks][2 * jj + 1]);
            afr[ks] = uu.v;
        }
    }

    f32x4 acc[3] = {(f32x4)0.f, (f32x4)0.f, (f32x4)0.f};
    f32x4 sdacc  = (f32x4)0.f;
    #pragma unroll
    for (int ks = 0; ks < NK; ++ks) {
        int k = ks * 32 + l4 * 8;
        #pragma unroll
        for (int t = 0; t < 3; ++t) {
            int n = (fg * 3 + t) * 16 + l15;
            bf16x8 bf = *(const bf16x8*)(WT + (size_t)n * KDIM + k);
            acc[t] = __builtin_amdgcn_mfma_f32_16x16x32_bf16(afr[ks], bf, acc[t], 0, 0, 0);
        }
        if (fg == 0) {
            bf16x8 bsd = *(const bf16x8*)(WsdT + (size_t)l15 * KDIM + k);
            sdacc = __builtin_amdgcn_mfma_f32_16x16x32_bf16(afr[ks], bsd, sdacc, 0, 0, 0);
        }
    }
    #pragma unroll
    for (int t = 0; t < 3; ++t) {
        int hf = (fg * 3 + t) * 16 + l15;
        size_t base = ((size_t)(b * 3 + (hf >> 6)) * 64 + (hf & 63)) * 1024 + nbase + l4 * 4;
        uint2 pk;
        pk.x = cvt_pk_bf16(acc[t][0], acc[t][1]);
        pk.y = cvt_pk_bf16(acc[t][2], acc[t][3]);
        *(uint2*)(VT + base) = pk;
    }
    if (fg == 0 && l15 < 6) {
        int h = l15 >> 1;
        float* dst = (l15 & 1) ? dt : st;
        size_t base = (size_t)(b * 3 + h) * 1024 + nbase + l4 * 4;
        #pragma unroll
        for (int r = 0; r < 4; ++r) dst[base + r] = sdacc[r];
    }
}

// ---------------------------------------------------------------------------
// Attention: grid 768 = (b*3+h)*32 + tile32. Block 256 = 4 waves; wave w
// handles j in [w*256,(w+1)*256) (8 iters), computing the FULL 32x64 partial
// (2 row-groups x 4 f-frags, 8 MFMA/iter). Deterministic LDS combine of the
// 4 partials + Z, then normalized write to hacc[b][n][h*64+f].
// ---------------------------------------------------------------------------
__global__ __launch_bounds__(256) void attn_head_kernel(
    const unsigned short* __restrict__ VT,
    const float* __restrict__ st, const float* __restrict__ dt,
    const unsigned int* __restrict__ maskw,   // [1024 rows][32 words]
    float* __restrict__ hacc)                 // [b][1024][192]
{
    __shared__ unsigned int lmask[32 * 33];
    __shared__ float pO[4][32 * 68];
    __shared__ float pZ[4][32];

    int bh    = blockIdx.x >> 5;              // b*3 + h
    int b     = bh / 3, h = bh % 3;
    int ibase = (blockIdx.x & 31) << 5;
    int w = threadIdx.x >> 6, l = threadIdx.x & 63;
    int l15 = l & 15, l4 = l >> 4;

    #pragma unroll
    for (int i = 0; i < 4; ++i) {
        int idx = threadIdx.x + i * 256;
        int row = idx >> 5, wd = idx & 31;
        lmask[row * 33 + wd] = maskw[(size_t)(ibase + row) * 32 + wd];
    }
    __syncthreads();

    float sv0 = st[(size_t)bh * 1024 + ibase + l15];
    float sv1 = st[(size_t)bh * 1024 + ibase + 16 + l15];
    const float* dptr = dt + (size_t)bh * 1024;
    const unsigned short* vbase = VT + (size_t)bh * 64 * 1024;

    f32x4 acc[2][4];
    #pragma unroll
    for (int rg = 0; rg < 2; ++rg)
        #pragma unroll
        for (int f4 = 0; f4 < 4; ++f4) acc[rg][f4] = (f32x4)0.f;
    float z0 = 0.f, z1 = 0.f;
    int jb = w * 256;

    #pragma unroll 2
    for (int it = 0; it < 8; ++it) {
        int k0 = jb + it * 32;
        int kk = k0 + l4 * 8;
        float4 da = *(const float4*)(dptr + kk);
        float4 db = *(const float4*)(dptr + kk + 4);
        unsigned mb0 = (lmask[l15 * 33 + (k0 >> 5)]        >> (l4 * 8)) & 0xffu;
        unsigned mb1 = (lmask[(16 + l15) * 33 + (k0 >> 5)] >> (l4 * 8)) & 0xffu;
        float dv[8] = {da.x, da.y, da.z, da.w, db.x, db.y, db.z, db.w};
        float p0[8], p1[8];
        #pragma unroll
        for (int j = 0; j < 8; ++j) {
            float t0 = sv0 + dv[j];
            t0 = fmaxf(t0, 0.2f * t0);
            t0 = ((mb0 >> j) & 1) ? t0 : -1e30f;
            p0[j] = fast_exp2(t0 * LOG2E);
            z0 += p0[j];
            float t1 = sv1 + dv[j];
            t1 = fmaxf(t1, 0.2f * t1);
            t1 = ((mb1 >> j) & 1) ? t1 : -1e30f;
            p1[j] = fast_exp2(t1 * LOG2E);
            z1 += p1[j];
        }
        union { unsigned u[4]; bf16x8 v; } ua, ub;
        #pragma unroll
        for (int jj = 0; jj < 4; ++jj) {
            ua.u[jj] = cvt_pk_bf16(p0[2 * jj], p0[2 * jj + 1]);
            ub.u[jj] = cvt_pk_bf16(p1[2 * jj], p1[2 * jj + 1]);
        }
        #pragma unroll
        for (int f4 = 0; f4 < 4; ++f4) {
            bf16x8 vb = *(const bf16x8*)(vbase + (size_t)(f4 * 16 + l15) * 1024 + kk);
            acc[0][f4] = __builtin_amdgcn_mfma_f32_16x16x32_bf16(ua.v, vb, acc[0][f4], 0, 0, 0);
            acc[1][f4] = __builtin_amdgcn_mfma_f32_16x16x32_bf16(ub.v, vb, acc[1][f4], 0, 0, 0);
        }
    }
    z0 += __shfl_xor(z0, 16); z0 += __shfl_xor(z0, 32);
    z1 += __shfl_xor(z1, 16); z1 += __shfl_xor(z1, 32);
    if (l4 == 0) pZ[w][l15] = z0;
    if (l4 == 1) pZ[w][16 + l15] = z1;
    #pragma unroll
    for (int rg = 0; rg < 2; ++rg)
        #pragma unroll
        for (int f4 = 0; f4 < 4; ++f4)
            #pragma unroll
            for (int r = 0; r < 4; ++r)
                pO[w][(rg * 16 + l4 * 4 + r) * 68 + f4 * 16 + l15] = acc[rg][f4][r];
    __syncthreads();

    int row = threadIdx.x >> 3;
    int fo  = (threadIdx.x & 7) * 8;
    float zs = pZ[0][row] + pZ[1][row] + pZ[2][row] + pZ[3][row];
    float rcp = 1.f / ((zs == 0.f) ? 1.f : zs);
    float o[8] = {0.f,0.f,0.f,0.f,0.f,0.f,0.f,0.f};
    #pragma unroll
    for (int ww = 0; ww < 4; ++ww) {
        const float* pp = &pO[ww][row * 68 + fo];
        float4 a = *(const float4*)(pp);
        float4 c = *(const float4*)(pp + 4);
        o[0] += a.x; o[1] += a.y; o[2] += a.z; o[3] += a.w;
        o[4] += c.x; o[5] += c.y; o[6] += c.z; o[7] += c.w;
    }
    float* op = hacc + (size_t)(b * 1024 + ibase + row) * 192 + h * 64 + fo;
    *(float4*)(op)     = make_float4(o[0] * rcp, o[1] * rcp, o[2] * rcp, o[3] * rcp);
    *(float4*)(op + 4) = make_float4(o[4] * rcp, o[5] * rcp, o[6] * rcp, o[7] * rcp);
}

// ---------------------------------------------------------------------------
// GRU + heads fused. sf2 = rsum + ELU(mean(hacc2)) built in-register;
// gi = sf2@wi.T, gh = hp16@wh.T; gates fp32; hnew written; hn bf16 staged in
// LDS; then actor/critic heads (path = w>>1). Grid 256 = (b, ntile32).
// ---------------------------------------------------------------------------
__global__ __launch_bounds__(256) void gruheads_kernel(
    const float* __restrict__ haccp, const float* __restrict__ rsum,
    const unsigned short* __restrict__ hp16,
    const unsigned short* __restrict__ wi16, const unsigned short* __restrict__ wh16,
    const float* __restrict__ bi, const float* __restrict__ bh,
    const float* __restrict__ hprev,
    const unsigned short* __restrict__ Wa1T, const unsigned short* __restrict__ Wc1T,
    const float* __restrict__ ba1, const float* __restrict__ Wa2, const float* __restrict__ ba2,
    const float* __restrict__ bc1, const float* __restrict__ Wc2, const float* __restrict__ bc2,
    float* __restrict__ hnew, float* __restrict__ probs, float* __restrict__ value)
{
    __shared__ unsigned short hnlds[32 * 72];

    int b     = blockIdx.x >> 5;
    int nbase = (blockIdx.x & 31) << 5;
    int w = threadIdx.x >> 6, l = threadIdx.x & 63;
    int rh = w & 1, g = w >> 1;
    int l15 = l & 15, l4 = l >> 4;
    int rowbase = b * 1024 + nbase + rh * 16;
    int arow = rowbase + l15;

    // build sf2 A-frags
    bf16x8 ai[2];
    #pragma unroll
    for (int ks = 0; ks < 2; ++ks) {
        int fb = ks * 32 + l4 * 8;
        const float* hp = haccp + (size_t)arow * 192 + fb;
        float4 a0 = *(const float4*)(hp);       float4 a1 = *(const float4*)(hp + 4);
        float4 c0 = *(const float4*)(hp + 64);  float4 c1 = *(const float4*)(hp + 68);
        float4 e0 = *(const float4*)(hp + 128); float4 e1 = *(const float4*)(hp + 132);
        const float* rp = rsum + (size_t)arow * 64 + fb;
        float4 r0 = *(const float4*)(rp);       float4 r1 = *(const float4*)(rp + 4);
        float m[8] = {a0.x + c0.x + e0.x, a0.y + c0.y + e0.y, a0.z + c0.z + e0.z, a0.w + c0.w + e0.w,
                      a1.x + c1.x + e1.x, a1.y + c1.y + e1.y, a1.z + c1.z + e1.z, a1.w + c1.w + e1.w};
        float rr[8] = {r0.x, r0.y, r0.z, r0.w, r1.x, r1.y, r1.z, r1.w};
        float sf[8];
        #pragma unroll
        for (int j = 0; j < 8; ++j) {
            float v = m[j] * (1.f / 3.f);
            v = (v > 0.f) ? v : (fast_exp2(v * LOG2E) - 1.f);
            sf[j] = v + rr[j];
        }
        union { unsigned u[4]; bf16x8 v; } uu;
        #pragma unroll
        for (int jj = 0; jj < 4; ++jj)
            uu.u[jj] = cvt_pk_bf16(sf[2 * jj], sf[2 * jj + 1]);
        ai[ks] = uu.v;
    }

    f32x4 gi[2][3], gh[2][3];
    #pragma unroll
    for (int t = 0; t < 2; ++t)
        #pragma unroll
        for (int q = 0; q < 3; ++q) { gi[t][q] = (f32x4)0.f; gh[t][q] = (f32x4)0.f; }

    #pragma unroll
    for (int ks = 0; ks < 2; ++ks) {
        int k = ks * 32 + l4 * 8;
        bf16x8 ah = *(const bf16x8*)(hp16 + (size_t)arow * 64 + k);
        #pragma unroll
        for (int t = 0; t < 2; ++t) {
            #pragma unroll
            for (int q = 0; q < 3; ++q) {
                int n = (q * 4 + g * 2 + t) * 16 + l15;
                bf16x8 bwi = *(const bf16x8*)(wi16 + (size_t)n * 64 + k);
                bf16x8 bwh = *(const bf16x8*)(wh16 + (size_t)n * 64 + k);
                gi[t][q] = __builtin_amdgcn_mfma_f32_16x16x32_bf16(ai[ks], bwi, gi[t][q], 0, 0, 0);
                gh[t][q] = __builtin_amdgcn_mfma_f32_16x16x32_bf16(ah,     bwh, gh[t][q], 0, 0, 0);
            }
        }
    }
    #pragma unroll
    for (int t = 0; t < 2; ++t) {
        int c = (g * 2 + t) * 16 + l15;
        float bir = bi[c], biz = bi[64 + c], bin = bi[128 + c];
        float bhr = bh[c], bhz = bh[64 + c], bhn = bh[128 + c];
        #pragma unroll
        for (int r = 0; r < 4; ++r) {
            int rloc = rh * 16 + 4 * l4 + r;
            int row = b * 1024 + nbase + rloc;
            float rr = (gi[t][0][r] + bir) + (gh[t][0][r] + bhr);
            float zz = (gi[t][1][r] + biz) + (gh[t][1][r] + bhz);
            float rg = 1.f / (1.f + fast_exp2(-rr * LOG2E));
            float zg = 1.f / (1.f + fast_exp2(-zz * LOG2E));
            float narg = (gi[t][2][r] + bin) + rg * (gh[t][2][r] + bhn);
            narg = fminf(fmaxf(narg, -15.f), 15.f);
            float e2 = fast_exp2(2.f * narg * LOG2E);
            float ng = (e2 - 1.f) / (e2 + 1.f);
            float hp = hprev[(size_t)row * 64 + c];
            float hv = (1.f - zg) * ng + zg * hp;
            hnew[(size_t)row * 64 + c] = hv;
            hnlds[rloc * 72 + c] = f2bf(hv);
        }
    }
    __syncthreads();

    // heads phase: path = g; waves (rh) cover both row halves
    const unsigned short* WT = g ? Wc1T : Wa1T;
    f32x4 acc[2] = {(f32x4)0.f, (f32x4)0.f};
    #pragma unroll
    for (int ks = 0; ks < 2; ++ks) {
        int k = ks * 32 + l4 * 8;
        bf16x8 a = *(const bf16x8*)(&hnlds[(rh * 16 + l15) * 72 + k]);
        #pragma unroll
        for (int t = 0; t < 2; ++t) {
            bf16x8 bf = *(const bf16x8*)(WT + (size_t)(t * 16 + l15) * 64 + k);
            acc[t] = __builtin_amdgcn_mfma_f32_16x16x32_bf16(a, bf, acc[t], 0, 0, 0);
        }
    }
    int rowbase2 = b * 1024 + nbase + rh * 16;
    if (g == 0) {
        float p0[4] = {0.f,0.f,0.f,0.f}, p1[4] = {0.f,0.f,0.f,0.f};
        #pragma unroll
        for (int t = 0; t < 2; ++t) {
            int c = t * 16 + l15;
            float b1 = ba1[c], w20 = Wa2[c * 2], w21 = Wa2[c * 2 + 1];
            #pragma unroll
            for (int r = 0; r < 4; ++r) {
                float v = fmaxf(acc[t][r] + b1, 0.f);
                p0[r] += v * w20; p1[r] += v * w21;
            }
        }
        #pragma unroll
        for (int r = 0; r < 4; ++r) {
            #pragma unroll
            for (int off = 1; off < 16; off <<= 1) {
                p0[r] += __shfl_xor(p0[r], off);
                p1[r] += __shfl_xor(p1[r], off);
            }
            float l0 = p0[r] + ba2[0], l1 = p1[r] + ba2[1];
            float mm = fmaxf(l0, l1);
            float e0 = fast_exp2((l0 - mm) * LOG2E);
            float e1 = fast_exp2((l1 - mm) * LOG2E);
            float s = 1.f / (e0 + e1);
            if (l15 == 0) {
                int row = rowbase2 + 4 * l4 + r;
                probs[(size_t)row * 2]     = e0 * s;
                probs[(size_t)row * 2 + 1] = e1 * s;
            }
        }
    } else {
        float pv[4] = {0.f,0.f,0.f,0.f};
        #pragma unroll
        for (int t = 0; t < 2; ++t) {
            int c = t * 16 + l15;
            float b1 = bc1[c], w2 = Wc2[c];
            #pragma unroll
            for (int r = 0; r < 4; ++r) {
                float v = fmaxf(acc[t][r] + b1, 0.f);
                pv[r] += v * w2;
            }
        }
        #pragma unroll
        for (int r = 0; r < 4; ++r) {
            #pragma unroll
            for (int off = 1; off < 16; off <<= 1) pv[r] += __shfl_xor(pv[r], off);
            if (l15 == 0) {
                int row = rowbase2 + 4 * l4 + r;
                value[row] = pv[r] + bc2[0];
            }
        }
    }
}

// ---------------------------------------------------------------------------
extern "C" void kernel_launch(void* const* d_in, const int* in_sizes, int n_in,
                              void* d_out, int out_size, void* d_ws, size_t ws_size,
                              hipStream_t stream)
{
    const float* x      = (const float*)d_in[0];
    const int*   adj    = (const int*)d_in[1];
    const float* h_prev = (const float*)d_in[2];
    const float* W0  = (const float*)d_in[3];
    const float* as0 = (const float*)d_in[4];
    const float* ad0 = (const float*)d_in[5];
    const float* W1  = (const float*)d_in[6];
    const float* as1 = (const float*)d_in[7];
    const float* ad1 = (const float*)d_in[8];
    const float* W2  = (const float*)d_in[9];
    const float* as2 = (const float*)d_in[10];
    const float* ad2 = (const float*)d_in[11];
    const float* gwi = (const float*)d_in[12];
    const float* gwh = (const float*)d_in[13];
    const float* gbi = (const float*)d_in[14];
    const float* gbh = (const float*)d_in[15];
    const float* Wa1 = (const float*)d_in[16];
    const float* ba1 = (const float*)d_in[17];
    const float* Wa2 = (const float*)d_in[18];
    const float* ba2 = (const float*)d_in[19];
    const float* Wc1 = (const float*)d_in[20];
    const float* bc1 = (const float*)d_in[21];
    const float* Wc2 = (const float*)d_in[22];
    const float* bc2 = (const float*)d_in[23];

    float* out   = (float*)d_out;
    float* probs = out;            // (8,1024,2)
    float* value = out + 16384;    // (8,1024,1)
    float* hnew  = out + 24576;    // (8,1024,64)

    char* p = (char*)d_ws;
    auto alloc = [&](size_t bytes) { char* q = p; p += (bytes + 255) & ~(size_t)255; return q; };
    auto* maskb = (unsigned long long*)alloc(16384 * 8);
    auto*  xpad  = (unsigned short*)alloc((size_t)NROWS * 32 * 2);
    auto*  hp16  = (unsigned short*)alloc((size_t)NROWS * 64 * 2);
    auto*  VT    = (unsigned short*)alloc((size_t)BB * 3 * 64 * 1024 * 2);
    float* st    = (float*)alloc((size_t)BB * 3 * 1024 * 4);
    float* dt    = (float*)alloc((size_t)BB * 3 * 1024 * 4);
    float* hacc  = (float*)alloc((size_t)BB * 1024 * 192 * 4);
    float* rsum  = (float*)alloc((size_t)NROWS * 64 * 4);
    auto*  W0Tp  = (unsigned short*)alloc(192 * 32 * 2);
    auto*  W1T   = (unsigned short*)alloc(192 * 64 * 2);
    auto*  W2T   = (unsigned short*)alloc(192 * 64 * 2);
    auto*  wi16  = (unsigned short*)alloc(192 * 64 * 2);
    auto*  wh16  = (unsigned short*)alloc(192 * 64 * 2);
    auto*  Wa1T  = (unsigned short*)alloc(32 * 64 * 2);
    auto*  Wc1T  = (unsigned short*)alloc(32 * 64 * 2);
    auto*  Wsd0  = (unsigned short*)alloc(16 * 32 * 2);
    auto*  Wsd1  = (unsigned short*)alloc(16 * 64 * 2);
    auto*  Wsd2  = (unsigned short*)alloc(16 * 64 * 2);
    (void)ws_size; (void)in_sizes; (void)n_in; (void)out_size;

    const unsigned int* maskw = (const unsigned int*)maskb;

    setup_kernel<<<1024, 256, 0, stream>>>(
        x, adj, h_prev, W0, as0, ad0, W1, as1, ad1, W2, as2, ad2,
        gwi, gwh, Wa1, Wc1,
        maskb, xpad, hp16, W0Tp, W1T, W2T, wi16, wh16, Wa1T, Wc1T,
        Wsd0, Wsd1, Wsd2);

    // Layer 0
    proj_kernel<32, 0><<<512, 256, 0, stream>>>(xpad, nullptr, nullptr, W0Tp, Wsd0, VT, st, dt);
    attn_head_kernel<<<768, 256, 0, stream>>>(VT, st, dt, maskw, hacc);
    // Layer 1: proj fuses combine of layer0 (rsum := E0)
    proj_kernel<64, 1><<<512, 256, 0, stream>>>(nullptr, hacc, rsum, W1T, Wsd1, VT, st, dt);
    attn_head_kernel<<<768, 256, 0, stream>>>(VT, st, dt, maskw, hacc);
    // Layer 2: proj fuses combine of layer1 (rsum := E0+E1)
    proj_kernel<64, 2><<<512, 256, 0, stream>>>(nullptr, hacc, rsum, W2T, Wsd2, VT, st, dt);
    attn_head_kernel<<<768, 256, 0, stream>>>(VT, st, dt, maskw, hacc);
    // GRU + heads (fuses combine of layer2)
    gruheads_kernel<<<256, 256, 0, stream>>>(
        hacc, rsum, hp16, wi16, wh16, gbi, gbh, h_prev,
        Wa1T, Wc1T, ba1, Wa2, ba2, bc1, Wc2, bc2, hnew, probs, value);
}

// Round 4
// 83.290 us; speedup vs baseline: 2.1592x; 1.3330x over previous
//
#include <hip/hip_runtime.h>
#include <hip/hip_bf16.h>
#include <stdint.h>

#define NHEADS 3
#define HID 64
#define NN 1024
#define BB 8
#define NROWS 8192   // B*N

using bf16x8 = __attribute__((ext_vector_type(8))) short;
using f32x4  = __attribute__((ext_vector_type(4))) float;

__device__ __forceinline__ unsigned short f2bf(float f) {
    unsigned u = __float_as_uint(f);
    u += 0x7fff + ((u >> 16) & 1);          // RNE
    return (unsigned short)(u >> 16);
}
// pure (non-volatile): lets the scheduler reorder/hoist around it
__device__ __forceinline__ unsigned cvt_pk_bf16(float lo, float hi) {
    unsigned r;
    asm("v_cvt_pk_bf16_f32 %0, %1, %2" : "=v"(r) : "v"(lo), "v"(hi));
    return r;
}
__device__ __forceinline__ float fast_exp2(float x) {
    return __builtin_amdgcn_exp2f(x);
}
#define LOG2E 1.44269504f

// ---------------------------------------------------------------------------
// Setup: pack adjacency bits, bf16 weights, pad x, precompute Wsd.
// ---------------------------------------------------------------------------
__global__ __launch_bounds__(256) void setup_kernel(
    const float* __restrict__ x, const int* __restrict__ adj, const float* __restrict__ h_prev,
    const float* __restrict__ W0, const float* __restrict__ as0, const float* __restrict__ ad0,
    const float* __restrict__ W1, const float* __restrict__ as1, const float* __restrict__ ad1,
    const float* __restrict__ W2, const float* __restrict__ as2, const float* __restrict__ ad2,
    const float* __restrict__ gwi, const float* __restrict__ gwh,
    const float* __restrict__ Wa1, const float* __restrict__ Wc1,
    unsigned long long* __restrict__ maskbits, unsigned short* __restrict__ xpad,
    unsigned short* __restrict__ hp16,
    unsigned short* __restrict__ W0Tp, unsigned short* __restrict__ W1T, unsigned short* __restrict__ W2T,
    unsigned short* __restrict__ wi16, unsigned short* __restrict__ wh16,
    unsigned short* __restrict__ Wa1T, unsigned short* __restrict__ Wc1T,
    unsigned short* __restrict__ Wsd0, unsigned short* __restrict__ Wsd1, unsigned short* __restrict__ Wsd2)
{
    int tid  = blockIdx.x * 256 + threadIdx.x;   // 0 .. 262143
    int lane = threadIdx.x & 63;
    int wv   = tid >> 6;

    #pragma unroll
    for (int i = 0; i < 4; ++i) {
        int w   = wv * 4 + i;
        int row = w >> 4, wc = w & 15;
        int j   = wc * 64 + lane;
        unsigned long long m = __ballot(adj[row * 1024 + j] > 0);
        if (lane == 0) maskbits[w] = m;
    }
    {
        int n = tid >> 5, k = tid & 31;
        xpad[tid] = (k < 3) ? f2bf(x[n * 3 + k]) : (unsigned short)0;
    }
    hp16[tid]          = f2bf(h_prev[tid]);
    hp16[tid + 262144] = f2bf(h_prev[tid + 262144]);
    if (tid < 12288) {
        int n = tid >> 6, k = tid & 63;
        W1T[tid]  = f2bf(W1[k * 192 + n]);
        W2T[tid]  = f2bf(W2[k * 192 + n]);
        wi16[tid] = f2bf(gwi[tid]);
        wh16[tid] = f2bf(gwh[tid]);
    }
    if (tid < 6144) {
        int n = tid >> 5, k = tid & 31;
        W0Tp[tid] = (k < 3) ? f2bf(W0[k * 192 + n]) : (unsigned short)0;
    }
    if (tid < 2048) {
        int n = tid >> 6, k = tid & 63;
        Wa1T[tid] = f2bf(Wa1[k * 32 + n]);
        Wc1T[tid] = f2bf(Wc1[k * 32 + n]);
    }
    if (tid < 16 * 32) {
        int c = tid >> 5, k = tid & 31;
        float v = 0.f;
        if (c < 6 && k < 3) {
            int h = c >> 1; const float* a = (c & 1) ? ad0 : as0;
            for (int f = 0; f < 64; ++f) v += W0[k * 192 + h * 64 + f] * a[h * 64 + f];
        }
        Wsd0[tid] = f2bf(v);
    }
    if (tid < 16 * 64) {
        int c = tid >> 6, k = tid & 63;
        float v1 = 0.f, v2 = 0.f;
        if (c < 6) {
            int h = c >> 1;
            const float* a1 = (c & 1) ? ad1 : as1;
            const float* a2 = (c & 1) ? ad2 : as2;
            for (int f = 0; f < 64; ++f) {
                v1 += W1[k * 192 + h * 64 + f] * a1[h * 64 + f];
                v2 += W2[k * 192 + h * 64 + f] * a2[h * 64 + f];
            }
        }
        Wsd1[tid] = f2bf(v1);
        Wsd2[tid] = f2bf(v2);
    }
}

// ---------------------------------------------------------------------------
// Projection. MODE 0: A from bf16 buffer (layer0). MODE 1: A = ELU(mean(hacc)),
// writes rsum = that. MODE 2: A = rsum + ELU(mean(hacc)), writes rsum = A.
// Grid 512; XCD-swizzled: b = blk&7, ntile16 = blk>>3. Block 256 = 4 waves.
// Writes VT bf16 [(b*3+h)*64+f][1024], st/dt f32 [b*3+h][1024].
// ---------------------------------------------------------------------------
template<int KDIM, int MODE>
__global__ __launch_bounds__(256) void proj_kernel(
    const unsigned short* __restrict__ A16,
    const float* __restrict__ haccp,          // [b][1024][192]
    float* __restrict__ rsum,                 // [8192][64]
    const unsigned short* __restrict__ WT,    // [192][KDIM]
    const unsigned short* __restrict__ WsdT,  // [16][KDIM]
    unsigned short* __restrict__ VT,
    float* __restrict__ st, float* __restrict__ dt)
{
    int b     = blockIdx.x & 7;               // XCD-local batch
    int nbase = (int)(blockIdx.x >> 3) << 4;
    int fg = threadIdx.x >> 6, l = threadIdx.x & 63;
    int l15 = l & 15, l4 = l >> 4;
    int row = b * 1024 + nbase + l15;
    constexpr int NK = KDIM / 32;

    bf16x8 afr[NK];
    if constexpr (MODE == 0) {
        #pragma unroll
        for (int ks = 0; ks < NK; ++ks)
            afr[ks] = *(const bf16x8*)(A16 + (size_t)row * KDIM + ks * 32 + l4 * 8);
    } else {
        float sf[2][8];
        #pragma unroll
        for (int ks = 0; ks < 2; ++ks) {
            int fb = ks * 32 + l4 * 8;
            const float* hp = haccp + (size_t)row * 192 + fb;
            float4 a0 = *(const float4*)(hp);       float4 a1 = *(const float4*)(hp + 4);
            float4 c0 = *(const float4*)(hp + 64);  float4 c1 = *(const float4*)(hp + 68);
            float4 e0 = *(const float4*)(hp + 128); float4 e1 = *(const float4*)(hp + 132);
            float m[8] = {a0.x + c0.x + e0.x, a0.y + c0.y + e0.y, a0.z + c0.z + e0.z, a0.w + c0.w + e0.w,
                          a1.x + c1.x + e1.x, a1.y + c1.y + e1.y, a1.z + c1.z + e1.z, a1.w + c1.w + e1.w};
            float r[8] = {0.f,0.f,0.f,0.f,0.f,0.f,0.f,0.f};
            if constexpr (MODE == 2) {
                const float* rp = rsum + (size_t)row * 64 + fb;
                float4 r0 = *(const float4*)(rp); float4 r1 = *(const float4*)(rp + 4);
                r[0]=r0.x; r[1]=r0.y; r[2]=r0.z; r[3]=r0.w;
                r[4]=r1.x; r[5]=r1.y; r[6]=r1.z; r[7]=r1.w;
            }
            #pragma unroll
            for (int j = 0; j < 8; ++j) {
                float v = m[j] * (1.f / 3.f);
                v = (v > 0.f) ? v : (fast_exp2(v * LOG2E) - 1.f);   // ELU
                sf[ks][j] = v + r[j];
            }
        }
        __syncthreads();           // all rsum reads done before any write
        if (fg == 0) {
            #pragma unroll
            for (int ks = 0; ks < 2; ++ks) {
                float* rp = rsum + (size_t)row * 64 + ks * 32 + l4 * 8;
                *(float4*)(rp)     = make_float4(sf[ks][0], sf[ks][1], sf[ks][2], sf[ks][3]);
                *(float4*)(rp + 4) = make_float4(sf[ks][4], sf[ks][5], sf[ks][6], sf[ks][7]);
            }
        }
        #pragma unroll
        for (int ks = 0; ks < 2; ++ks) {
            union { unsigned u[4]; bf16x8 v; } uu;
            #pragma unroll
            for (int jj = 0; jj < 4; ++jj)
                uu.u[jj] = cvt_pk_bf16(sf[ks][2 * jj], sf[ks][2 * jj + 1]);
            afr[ks] = uu.v;
        }
    }

    f32x4 acc[3] = {(f32x4)0.f, (f32x4)0.f, (f32x4)0.f};
    f32x4 sdacc  = (f32x4)0.f;
    #pragma unroll
    for (int ks = 0; ks < NK; ++ks) {
        int k = ks * 32 + l4 * 8;
        #pragma unroll
        for (int t = 0; t < 3; ++t) {
            int n = (fg * 3 + t) * 16 + l15;
            bf16x8 bf = *(const bf16x8*)(WT + (size_t)n * KDIM + k);
            acc[t] = __builtin_amdgcn_mfma_f32_16x16x32_bf16(afr[ks], bf, acc[t], 0, 0, 0);
        }
        if (fg == 0) {
            bf16x8 bsd = *(const bf16x8*)(WsdT + (size_t)l15 * KDIM + k);
            sdacc = __builtin_amdgcn_mfma_f32_16x16x32_bf16(afr[ks], bsd, sdacc, 0, 0, 0);
        }
    }
    #pragma unroll
    for (int t = 0; t < 3; ++t) {
        int hf = (fg * 3 + t) * 16 + l15;
        size_t base = ((size_t)(b * 3 + (hf >> 6)) * 64 + (hf & 63)) * 1024 + nbase + l4 * 4;
        uint2 pk;
        pk.x = cvt_pk_bf16(acc[t][0], acc[t][1]);
        pk.y = cvt_pk_bf16(acc[t][2], acc[t][3]);
        *(uint2*)(VT + base) = pk;
    }
    if (fg == 0 && l15 < 6) {
        int h = l15 >> 1;
        float* dst = (l15 & 1) ? dt : st;
        size_t base = (size_t)(b * 3 + h) * 1024 + nbase + l4 * 4;
        #pragma unroll
        for (int r = 0; r < 4; ++r) dst[base + r] = sdacc[r];
    }
}

// ---------------------------------------------------------------------------
// Attention: grid 768, XCD-swizzled so each bh's 32 tiles land on ONE XCD
// (b = xcd = blk&7, h = (blk>>3)/32, tile = (blk>>3)&31). Block 256 = 4
// waves; wave w covers j in [w*256,(w+1)*256) (8 iters), full 32x64 partial.
// d (pre-scaled by log2e) staged in LDS; manual 2-stage load pipeline;
// select-after-exp keeps the mask off the exp critical path. Deterministic
// LDS combine of 4 partials + Z, normalized write to hacc[b][n][h*64+f].
// ---------------------------------------------------------------------------
__global__ __launch_bounds__(256) void attn_head_kernel(
    const unsigned short* __restrict__ VT,
    const float* __restrict__ st, const float* __restrict__ dt,
    const unsigned int* __restrict__ maskw,   // [1024 rows][32 words]
    float* __restrict__ hacc)                 // [b][1024][192]
{
    __shared__ float dlds[1024];
    __shared__ unsigned int lmask[32 * 33];
    __shared__ float pO[4][32 * 68];
    __shared__ float pZ[4][32];

    int b     = blockIdx.x & 7;               // = XCD
    int q     = blockIdx.x >> 3;              // 0..95
    int h     = q >> 5;
    int bh    = b * 3 + h;
    int ibase = (q & 31) << 5;
    int w = threadIdx.x >> 6, l = threadIdx.x & 63;
    int l15 = l & 15, l4 = l >> 4;

    // stage mask words (stride 33) and scaled d
    #pragma unroll
    for (int i = 0; i < 4; ++i) {
        int idx = threadIdx.x + i * 256;
        int row = idx >> 5, wd = idx & 31;
        lmask[row * 33 + wd] = maskw[(size_t)(ibase + row) * 32 + wd];
    }
    {
        int t4 = threadIdx.x * 4;
        float4 dv4 = *(const float4*)(dt + (size_t)bh * 1024 + t4);
        *(float4*)(dlds + t4) = make_float4(dv4.x * LOG2E, dv4.y * LOG2E,
                                            dv4.z * LOG2E, dv4.w * LOG2E);
    }
    __syncthreads();

    float sv0 = st[(size_t)bh * 1024 + ibase + l15]      * LOG2E;
    float sv1 = st[(size_t)bh * 1024 + ibase + 16 + l15] * LOG2E;
    const unsigned short* vbase = VT + (size_t)bh * 64 * 1024;

    f32x4 acc[2][4];
    #pragma unroll
    for (int rg = 0; rg < 2; ++rg)
        #pragma unroll
        for (int f4 = 0; f4 < 4; ++f4) acc[rg][f4] = (f32x4)0.f;
    float z0 = 0.f, z1 = 0.f;
    int jb = w * 256;
    int w8 = w * 8;

    auto ldstep = [&](int it, float4& A, float4& B,
                      bf16x8& Va, bf16x8& Vb, bf16x8& Vc, bf16x8& Vd) {
        int kk = jb + it * 32 + l4 * 8;
        A  = *(const float4*)(dlds + kk);
        B  = *(const float4*)(dlds + kk + 4);
        Va = *(const bf16x8*)(vbase + (size_t)(l15)      * 1024 + kk);
        Vb = *(const bf16x8*)(vbase + (size_t)(16 + l15) * 1024 + kk);
        Vc = *(const bf16x8*)(vbase + (size_t)(32 + l15) * 1024 + kk);
        Vd = *(const bf16x8*)(vbase + (size_t)(48 + l15) * 1024 + kk);
    };
    auto cstep = [&](int it, float4 A, float4 B,
                     bf16x8 Va, bf16x8 Vb, bf16x8 Vc, bf16x8 Vd) {
        unsigned m0 = (lmask[l15 * 33 + w8 + it]        >> (l4 * 8)) & 0xffu;
        unsigned m1 = (lmask[(16 + l15) * 33 + w8 + it] >> (l4 * 8)) & 0xffu;
        float dvv[8] = {A.x, A.y, A.z, A.w, B.x, B.y, B.z, B.w};
        float p0[8], p1[8];
        #pragma unroll
        for (int j = 0; j < 8; ++j) {
            float t0 = sv0 + dvv[j];
            float e0 = fast_exp2(fmaxf(t0, 0.2f * t0));
            p0[j] = ((m0 >> j) & 1) ? e0 : 0.f;
            z0 += p0[j];
            float t1 = sv1 + dvv[j];
            float e1 = fast_exp2(fmaxf(t1, 0.2f * t1));
            p1[j] = ((m1 >> j) & 1) ? e1 : 0.f;
            z1 += p1[j];
        }
        union { unsigned u[4]; bf16x8 v; } ua, ub;
        #pragma unroll
        for (int jj = 0; jj < 4; ++jj) {
            ua.u[jj] = cvt_pk_bf16(p0[2 * jj], p0[2 * jj + 1]);
            ub.u[jj] = cvt_pk_bf16(p1[2 * jj], p1[2 * jj + 1]);
        }
        acc[0][0] = __builtin_amdgcn_mfma_f32_16x16x32_bf16(ua.v, Va, acc[0][0], 0, 0, 0);
        acc[0][1] = __builtin_amdgcn_mfma_f32_16x16x32_bf16(ua.v, Vb, acc[0][1], 0, 0, 0);
        acc[0][2] = __builtin_amdgcn_mfma_f32_16x16x32_bf16(ua.v, Vc, acc[0][2], 0, 0, 0);
        acc[0][3] = __builtin_amdgcn_mfma_f32_16x16x32_bf16(ua.v, Vd, acc[0][3], 0, 0, 0);
        acc[1][0] = __builtin_amdgcn_mfma_f32_16x16x32_bf16(ub.v, Va, acc[1][0], 0, 0, 0);
        acc[1][1] = __builtin_amdgcn_mfma_f32_16x16x32_bf16(ub.v, Vb, acc[1][1], 0, 0, 0);
        acc[1][2] = __builtin_amdgcn_mfma_f32_16x16x32_bf16(ub.v, Vc, acc[1][2], 0, 0, 0);
        acc[1][3] = __builtin_amdgcn_mfma_f32_16x16x32_bf16(ub.v, Vd, acc[1][3], 0, 0, 0);
    };

    // 2-stage software pipeline over 8 iterations
    float4 A0, B0, A1, B1;
    bf16x8 Va0, Vb0, Vc0, Vd0, Va1, Vb1, Vc1, Vd1;
    ldstep(0, A0, B0, Va0, Vb0, Vc0, Vd0);
    #pragma unroll
    for (int it = 0; it < 8; it += 2) {
        if (it + 1 < 8) ldstep(it + 1, A1, B1, Va1, Vb1, Vc1, Vd1);
        cstep(it, A0, B0, Va0, Vb0, Vc0, Vd0);
        if (it + 2 < 8) ldstep(it + 2, A0, B0, Va0, Vb0, Vc0, Vd0);
        if (it + 1 < 8) cstep(it + 1, A1, B1, Va1, Vb1, Vc1, Vd1);
    }

    z0 += __shfl_xor(z0, 16); z0 += __shfl_xor(z0, 32);
    z1 += __shfl_xor(z1, 16); z1 += __shfl_xor(z1, 32);
    if (l4 == 0) pZ[w][l15] = z0;
    if (l4 == 1) pZ[w][16 + l15] = z1;
    #pragma unroll
    for (int rg = 0; rg < 2; ++rg)
        #pragma unroll
        for (int f4 = 0; f4 < 4; ++f4)
            #pragma unroll
            for (int r = 0; r < 4; ++r)
                pO[w][(rg * 16 + l4 * 4 + r) * 68 + f4 * 16 + l15] = acc[rg][f4][r];
    __syncthreads();

    int row = threadIdx.x >> 3;
    int fo  = (threadIdx.x & 7) * 8;
    float zs = pZ[0][row] + pZ[1][row] + pZ[2][row] + pZ[3][row];
    float rcp = 1.f / ((zs == 0.f) ? 1.f : zs);
    float o[8] = {0.f,0.f,0.f,0.f,0.f,0.f,0.f,0.f};
    #pragma unroll
    for (int ww = 0; ww < 4; ++ww) {
        const float* pp = &pO[ww][row * 68 + fo];
        float4 a = *(const float4*)(pp);
        float4 c = *(const float4*)(pp + 4);
        o[0] += a.x; o[1] += a.y; o[2] += a.z; o[3] += a.w;
        o[4] += c.x; o[5] += c.y; o[6] += c.z; o[7] += c.w;
    }
    float* op = hacc + (size_t)(b * 1024 + ibase + row) * 192 + h * 64 + fo;
    *(float4*)(op)     = make_float4(o[0] * rcp, o[1] * rcp, o[2] * rcp, o[3] * rcp);
    *(float4*)(op + 4) = make_float4(o[4] * rcp, o[5] * rcp, o[6] * rcp, o[7] * rcp);
}

// ---------------------------------------------------------------------------
// GRU + heads fused. sf2 = rsum + ELU(mean(hacc2)) built in-register;
// gi = sf2@wi.T, gh = hp16@wh.T; gates fp32; hnew written; hn bf16 staged in
// LDS; then actor/critic heads (path = w>>1). Grid 256, XCD-swizzled.
// ---------------------------------------------------------------------------
__global__ __launch_bounds__(256) void gruheads_kernel(
    const float* __restrict__ haccp, const float* __restrict__ rsum,
    const unsigned short* __restrict__ hp16,
    const unsigned short* __restrict__ wi16, const unsigned short* __restrict__ wh16,
    const float* __restrict__ bi, const float* __restrict__ bh,
    const float* __restrict__ hprev,
    const unsigned short* __restrict__ Wa1T, const unsigned short* __restrict__ Wc1T,
    const float* __restrict__ ba1, const float* __restrict__ Wa2, const float* __restrict__ ba2,
    const float* __restrict__ bc1, const float* __restrict__ Wc2, const float* __restrict__ bc2,
    float* __restrict__ hnew, float* __restrict__ probs, float* __restrict__ value)
{
    __shared__ unsigned short hnlds[32 * 72];

    int b     = blockIdx.x & 7;
    int nbase = (int)(blockIdx.x >> 3) << 5;
    int w = threadIdx.x >> 6, l = threadIdx.x & 63;
    int rh = w & 1, g = w >> 1;
    int l15 = l & 15, l4 = l >> 4;
    int rowbase = b * 1024 + nbase + rh * 16;
    int arow = rowbase + l15;

    // build sf2 A-frags
    bf16x8 ai[2];
    #pragma unroll
    for (int ks = 0; ks < 2; ++ks) {
        int fb = ks * 32 + l4 * 8;
        const float* hp = haccp + (size_t)arow * 192 + fb;
        float4 a0 = *(const float4*)(hp);       float4 a1 = *(const float4*)(hp + 4);
        float4 c0 = *(const float4*)(hp + 64);  float4 c1 = *(const float4*)(hp + 68);
        float4 e0 = *(const float4*)(hp + 128); float4 e1 = *(const float4*)(hp + 132);
        const float* rp = rsum + (size_t)arow * 64 + fb;
        float4 r0 = *(const float4*)(rp);       float4 r1 = *(const float4*)(rp + 4);
        float m[8] = {a0.x + c0.x + e0.x, a0.y + c0.y + e0.y, a0.z + c0.z + e0.z, a0.w + c0.w + e0.w,
                      a1.x + c1.x + e1.x, a1.y + c1.y + e1.y, a1.z + c1.z + e1.z, a1.w + c1.w + e1.w};
        float rr[8] = {r0.x, r0.y, r0.z, r0.w, r1.x, r1.y, r1.z, r1.w};
        float sf[8];
        #pragma unroll
        for (int j = 0; j < 8; ++j) {
            float v = m[j] * (1.f / 3.f);
            v = (v > 0.f) ? v : (fast_exp2(v * LOG2E) - 1.f);
            sf[j] = v + rr[j];
        }
        union { unsigned u[4]; bf16x8 v; } uu;
        #pragma unroll
        for (int jj = 0; jj < 4; ++jj)
            uu.u[jj] = cvt_pk_bf16(sf[2 * jj], sf[2 * jj + 1]);
        ai[ks] = uu.v;
    }

    f32x4 gi[2][3], gh[2][3];
    #pragma unroll
    for (int t = 0; t < 2; ++t)
        #pragma unroll
        for (int q = 0; q < 3; ++q) { gi[t][q] = (f32x4)0.f; gh[t][q] = (f32x4)0.f; }

    #pragma unroll
    for (int ks = 0; ks < 2; ++ks) {
        int k = ks * 32 + l4 * 8;
        bf16x8 ah = *(const bf16x8*)(hp16 + (size_t)arow * 64 + k);
        #pragma unroll
        for (int t = 0; t < 2; ++t) {
            #pragma unroll
            for (int q = 0; q < 3; ++q) {
                int n = (q * 4 + g * 2 + t) * 16 + l15;
                bf16x8 bwi = *(const bf16x8*)(wi16 + (size_t)n * 64 + k);
                bf16x8 bwh = *(const bf16x8*)(wh16 + (size_t)n * 64 + k);
                gi[t][q] = __builtin_amdgcn_mfma_f32_16x16x32_bf16(ai[ks], bwi, gi[t][q], 0, 0, 0);
                gh[t][q] = __builtin_amdgcn_mfma_f32_16x16x32_bf16(ah,     bwh, gh[t][q], 0, 0, 0);
            }
        }
    }
    #pragma unroll
    for (int t = 0; t < 2; ++t) {
        int c = (g * 2 + t) * 16 + l15;
        float bir = bi[c], biz = bi[64 + c], bin = bi[128 + c];
        float bhr = bh[c], bhz = bh[64 + c], bhn = bh[128 + c];
        #pragma unroll
        for (int r = 0; r < 4; ++r) {
            int rloc = rh * 16 + 4 * l4 + r;
            int row = b * 1024 + nbase + rloc;
            float rr = (gi[t][0][r] + bir) + (gh[t][0][r] + bhr);
            float zz = (gi[t][1][r] + biz) + (gh[t][1][r] + bhz);
            float rg = 1.f / (1.f + fast_exp2(-rr * LOG2E));
            float zg = 1.f / (1.f + fast_exp2(-zz * LOG2E));
            float narg = (gi[t][2][r] + bin) + rg * (gh[t][2][r] + bhn);
            narg = fminf(fmaxf(narg, -15.f), 15.f);
            float e2 = fast_exp2(2.f * narg * LOG2E);
            float ng = (e2 - 1.f) / (e2 + 1.f);
            float hp = hprev[(size_t)row * 64 + c];
            float hv = (1.f - zg) * ng + zg * hp;
            hnew[(size_t)row * 64 + c] = hv;
            hnlds[rloc * 72 + c] = f2bf(hv);
        }
    }
    __syncthreads();

    // heads phase: path = g; waves (rh) cover both row halves
    const unsigned short* WT = g ? Wc1T : Wa1T;
    f32x4 acc[2] = {(f32x4)0.f, (f32x4)0.f};
    #pragma unroll
    for (int ks = 0; ks < 2; ++ks) {
        int k = ks * 32 + l4 * 8;
        bf16x8 a = *(const bf16x8*)(&hnlds[(rh * 16 + l15) * 72 + k]);
        #pragma unroll
        for (int t = 0; t < 2; ++t) {
            bf16x8 bf = *(const bf16x8*)(WT + (size_t)(t * 16 + l15) * 64 + k);
            acc[t] = __builtin_amdgcn_mfma_f32_16x16x32_bf16(a, bf, acc[t], 0, 0, 0);
        }
    }
    int rowbase2 = b * 1024 + nbase + rh * 16;
    if (g == 0) {
        float p0[4] = {0.f,0.f,0.f,0.f}, p1[4] = {0.f,0.f,0.f,0.f};
        #pragma unroll
        for (int t = 0; t < 2; ++t) {
            int c = t * 16 + l15;
            float b1 = ba1[c], w20 = Wa2[c * 2], w21 = Wa2[c * 2 + 1];
            #pragma unroll
            for (int r = 0; r < 4; ++r) {
                float v = fmaxf(acc[t][r] + b1, 0.f);
                p0[r] += v * w20; p1[r] += v * w21;
            }
        }
        #pragma unroll
        for (int r = 0; r < 4; ++r) {
            #pragma unroll
            for (int off = 1; off < 16; off <<= 1) {
                p0[r] += __shfl_xor(p0[r], off);
                p1[r] += __shfl_xor(p1[r], off);
            }
            float l0 = p0[r] + ba2[0], l1 = p1[r] + ba2[1];
            float mm = fmaxf(l0, l1);
            float e0 = fast_exp2((l0 - mm) * LOG2E);
            float e1 = fast_exp2((l1 - mm) * LOG2E);
            float s = 1.f / (e0 + e1);
            if (l15 == 0) {
                int row = rowbase2 + 4 * l4 + r;
                probs[(size_t)row * 2]     = e0 * s;
                probs[(size_t)row * 2 + 1] = e1 * s;
            }
        }
    } else {
        float pv[4] = {0.f,0.f,0.f,0.f};
        #pragma unroll
        for (int t = 0; t < 2; ++t) {
            int c = t * 16 + l15;
            float b1 = bc1[c], w2 = Wc2[c];
            #pragma unroll
            for (int r = 0; r < 4; ++r) {
                float v = fmaxf(acc[t][r] + b1, 0.f);
                pv[r] += v * w2;
            }
        }
        #pragma unroll
        for (int r = 0; r < 4; ++r) {
            #pragma unroll
            for (int off = 1; off < 16; off <<= 1) pv[r] += __shfl_xor(pv[r], off);
            if (l15 == 0) {
                int row = rowbase2 + 4 * l4 + r;
                value[row] = pv[r] + bc2[0];
            }
        }
    }
}

// ---------------------------------------------------------------------------
extern "C" void kernel_launch(void* const* d_in, const int* in_sizes, int n_in,
                              void* d_out, int out_size, void* d_ws, size_t ws_size,
                              hipStream_t stream)
{
    const float* x      = (const float*)d_in[0];
    const int*   adj    = (const int*)d_in[1];
    const float* h_prev = (const float*)d_in[2];
    const float* W0  = (const float*)d_in[3];
    const float* as0 = (const float*)d_in[4];
    const float* ad0 = (const float*)d_in[5];
    const float* W1  = (const float*)d_in[6];
    const float* as1 = (const float*)d_in[7];
    const float* ad1 = (const float*)d_in[8];
    const float* W2  = (const float*)d_in[9];
    const float* as2 = (const float*)d_in[10];
    const float* ad2 = (const float*)d_in[11];
    const float* gwi = (const float*)d_in[12];
    const float* gwh = (const float*)d_in[13];
    const float* gbi = (const float*)d_in[14];
    const float* gbh = (const float*)d_in[15];
    const float* Wa1 = (const float*)d_in[16];
    const float* ba1 = (const float*)d_in[17];
    const float* Wa2 = (const float*)d_in[18];
    const float* ba2 = (const float*)d_in[19];
    const float* Wc1 = (const float*)d_in[20];
    const float* bc1 = (const float*)d_in[21];
    const float* Wc2 = (const float*)d_in[22];
    const float* bc2 = (const float*)d_in[23];

    float* out   = (float*)d_out;
    float* probs = out;            // (8,1024,2)
    float* value = out + 16384;    // (8,1024,1)
    float* hnew  = out + 24576;    // (8,1024,64)

    char* p = (char*)d_ws;
    auto alloc = [&](size_t bytes) { char* q = p; p += (bytes + 255) & ~(size_t)255; return q; };
    auto* maskb = (unsigned long long*)alloc(16384 * 8);
    auto*  xpad  = (unsigned short*)alloc((size_t)NROWS * 32 * 2);
    auto*  hp16  = (unsigned short*)alloc((size_t)NROWS * 64 * 2);
    auto*  VT    = (unsigned short*)alloc((size_t)BB * 3 * 64 * 1024 * 2);
    float* st    = (float*)alloc((size_t)BB * 3 * 1024 * 4);
    float* dt    = (float*)alloc((size_t)BB * 3 * 1024 * 4);
    float* hacc  = (float*)alloc((size_t)BB * 1024 * 192 * 4);
    float* rsum  = (float*)alloc((size_t)NROWS * 64 * 4);
    auto*  W0Tp  = (unsigned short*)alloc(192 * 32 * 2);
    auto*  W1T   = (unsigned short*)alloc(192 * 64 * 2);
    auto*  W2T   = (unsigned short*)alloc(192 * 64 * 2);
    auto*  wi16  = (unsigned short*)alloc(192 * 64 * 2);
    auto*  wh16  = (unsigned short*)alloc(192 * 64 * 2);
    auto*  Wa1T  = (unsigned short*)alloc(32 * 64 * 2);
    auto*  Wc1T  = (unsigned short*)alloc(32 * 64 * 2);
    auto*  Wsd0  = (unsigned short*)alloc(16 * 32 * 2);
    auto*  Wsd1  = (unsigned short*)alloc(16 * 64 * 2);
    auto*  Wsd2  = (unsigned short*)alloc(16 * 64 * 2);
    (void)ws_size; (void)in_sizes; (void)n_in; (void)out_size;

    const unsigned int* maskw = (const unsigned int*)maskb;

    setup_kernel<<<1024, 256, 0, stream>>>(
        x, adj, h_prev, W0, as0, ad0, W1, as1, ad1, W2, as2, ad2,
        gwi, gwh, Wa1, Wc1,
        maskb, xpad, hp16, W0Tp, W1T, W2T, wi16, wh16, Wa1T, Wc1T,
        Wsd0, Wsd1, Wsd2);

    // Layer 0
    proj_kernel<32, 0><<<512, 256, 0, stream>>>(xpad, nullptr, nullptr, W0Tp, Wsd0, VT, st, dt);
    attn_head_kernel<<<768, 256, 0, stream>>>(VT, st, dt, maskw, hacc);
    // Layer 1: proj fuses combine of layer0 (rsum := E0)
    proj_kernel<64, 1><<<512, 256, 0, stream>>>(nullptr, hacc, rsum, W1T, Wsd1, VT, st, dt);
    attn_head_kernel<<<768, 256, 0, stream>>>(VT, st, dt, maskw, hacc);
    // Layer 2: proj fuses combine of layer1 (rsum := E0+E1)
    proj_kernel<64, 2><<<512, 256, 0, stream>>>(nullptr, hacc, rsum, W2T, Wsd2, VT, st, dt);
    attn_head_kernel<<<768, 256, 0, stream>>>(VT, st, dt, maskw, hacc);
    // GRU + heads (fuses combine of layer2)
    gruheads_kernel<<<256, 256, 0, stream>>>(
        hacc, rsum, hp16, wi16, wh16, gbi, gbh, h_prev,
        Wa1T, Wc1T, ba1, Wa2, ba2, bc1, Wc2, bc2, hnew, probs, value);
}

// Round 5
// 83.247 us; speedup vs baseline: 2.1603x; 1.0005x over previous
//
#include <hip/hip_runtime.h>
#include <hip/hip_bf16.h>
#include <stdint.h>

#define NHEADS 3
#define HID 64
#define NN 1024
#define BB 8
#define NROWS 8192   // B*N

using bf16x8 = __attribute__((ext_vector_type(8))) short;
using f32x4  = __attribute__((ext_vector_type(4))) float;

__device__ __forceinline__ unsigned short f2bf(float f) {
    unsigned u = __float_as_uint(f);
    u += 0x7fff + ((u >> 16) & 1);          // RNE
    return (unsigned short)(u >> 16);
}
// pure (non-volatile): lets the scheduler reorder/hoist around it
__device__ __forceinline__ unsigned cvt_pk_bf16(float lo, float hi) {
    unsigned r;
    asm("v_cvt_pk_bf16_f32 %0, %1, %2" : "=v"(r) : "v"(lo), "v"(hi));
    return r;
}
__device__ __forceinline__ float fast_exp2(float x) {
    return __builtin_amdgcn_exp2f(x);
}
#define LOG2E 1.44269504f

// ---------------------------------------------------------------------------
// Setup: pack adjacency bits, bf16 weights, pad x, precompute Wsd.
// ---------------------------------------------------------------------------
__global__ __launch_bounds__(256) void setup_kernel(
    const float* __restrict__ x, const int* __restrict__ adj, const float* __restrict__ h_prev,
    const float* __restrict__ W0, const float* __restrict__ as0, const float* __restrict__ ad0,
    const float* __restrict__ W1, const float* __restrict__ as1, const float* __restrict__ ad1,
    const float* __restrict__ W2, const float* __restrict__ as2, const float* __restrict__ ad2,
    const float* __restrict__ gwi, const float* __restrict__ gwh,
    const float* __restrict__ Wa1, const float* __restrict__ Wc1,
    unsigned long long* __restrict__ maskbits, unsigned short* __restrict__ xpad,
    unsigned short* __restrict__ hp16,
    unsigned short* __restrict__ W0Tp, unsigned short* __restrict__ W1T, unsigned short* __restrict__ W2T,
    unsigned short* __restrict__ wi16, unsigned short* __restrict__ wh16,
    unsigned short* __restrict__ Wa1T, unsigned short* __restrict__ Wc1T,
    unsigned short* __restrict__ Wsd0, unsigned short* __restrict__ Wsd1, unsigned short* __restrict__ Wsd2)
{
    int tid  = blockIdx.x * 256 + threadIdx.x;   // 0 .. 262143
    int lane = threadIdx.x & 63;
    int wv   = tid >> 6;

    #pragma unroll
    for (int i = 0; i < 4; ++i) {
        int w   = wv * 4 + i;
        int row = w >> 4, wc = w & 15;
        int j   = wc * 64 + lane;
        unsigned long long m = __ballot(adj[row * 1024 + j] > 0);
        if (lane == 0) maskbits[w] = m;
    }
    {
        int n = tid >> 5, k = tid & 31;
        xpad[tid] = (k < 3) ? f2bf(x[n * 3 + k]) : (unsigned short)0;
    }
    hp16[tid]          = f2bf(h_prev[tid]);
    hp16[tid + 262144] = f2bf(h_prev[tid + 262144]);
    if (tid < 12288) {
        int n = tid >> 6, k = tid & 63;
        W1T[tid]  = f2bf(W1[k * 192 + n]);
        W2T[tid]  = f2bf(W2[k * 192 + n]);
        wi16[tid] = f2bf(gwi[tid]);
        wh16[tid] = f2bf(gwh[tid]);
    }
    if (tid < 6144) {
        int n = tid >> 5, k = tid & 31;
        W0Tp[tid] = (k < 3) ? f2bf(W0[k * 192 + n]) : (unsigned short)0;
    }
    if (tid < 2048) {
        int n = tid >> 6, k = tid & 63;
        Wa1T[tid] = f2bf(Wa1[k * 32 + n]);
        Wc1T[tid] = f2bf(Wc1[k * 32 + n]);
    }
    if (tid < 16 * 32) {
        int c = tid >> 5, k = tid & 31;
        float v = 0.f;
        if (c < 6 && k < 3) {
            int h = c >> 1; const float* a = (c & 1) ? ad0 : as0;
            for (int f = 0; f < 64; ++f) v += W0[k * 192 + h * 64 + f] * a[h * 64 + f];
        }
        Wsd0[tid] = f2bf(v);
    }
    if (tid < 16 * 64) {
        int c = tid >> 6, k = tid & 63;
        float v1 = 0.f, v2 = 0.f;
        if (c < 6) {
            int h = c >> 1;
            const float* a1 = (c & 1) ? ad1 : as1;
            const float* a2 = (c & 1) ? ad2 : as2;
            for (int f = 0; f < 64; ++f) {
                v1 += W1[k * 192 + h * 64 + f] * a1[h * 64 + f];
                v2 += W2[k * 192 + h * 64 + f] * a2[h * 64 + f];
            }
        }
        Wsd1[tid] = f2bf(v1);
        Wsd2[tid] = f2bf(v2);
    }
}

// ---------------------------------------------------------------------------
// Projection. MODE 0: A from bf16 buffer (layer0). MODE 1: A = ELU(mean(hacc)),
// writes rsum = that. MODE 2: A = rsum + ELU(mean(hacc)), writes rsum = A.
// Grid 512; XCD-swizzled: b = blk&7, ntile16 = blk>>3. Block 256 = 4 waves.
// ---------------------------------------------------------------------------
template<int KDIM, int MODE>
__global__ __launch_bounds__(256) void proj_kernel(
    const unsigned short* __restrict__ A16,
    const float* __restrict__ haccp,          // [b][1024][192]
    float* __restrict__ rsum,                 // [8192][64]
    const unsigned short* __restrict__ WT,    // [192][KDIM]
    const unsigned short* __restrict__ WsdT,  // [16][KDIM]
    unsigned short* __restrict__ VT,
    float* __restrict__ st, float* __restrict__ dt)
{
    int b     = blockIdx.x & 7;               // XCD-local batch
    int nbase = (int)(blockIdx.x >> 3) << 4;
    int fg = threadIdx.x >> 6, l = threadIdx.x & 63;
    int l15 = l & 15, l4 = l >> 4;
    int row = b * 1024 + nbase + l15;
    constexpr int NK = KDIM / 32;

    bf16x8 afr[NK];
    if constexpr (MODE == 0) {
        #pragma unroll
        for (int ks = 0; ks < NK; ++ks)
            afr[ks] = *(const bf16x8*)(A16 + (size_t)row * KDIM + ks * 32 + l4 * 8);
    } else {
        float sf[2][8];
        #pragma unroll
        for (int ks = 0; ks < 2; ++ks) {
            int fb = ks * 32 + l4 * 8;
            const float* hp = haccp + (size_t)row * 192 + fb;
            float4 a0 = *(const float4*)(hp);       float4 a1 = *(const float4*)(hp + 4);
            float4 c0 = *(const float4*)(hp + 64);  float4 c1 = *(const float4*)(hp + 68);
            float4 e0 = *(const float4*)(hp + 128); float4 e1 = *(const float4*)(hp + 132);
            float m[8] = {a0.x + c0.x + e0.x, a0.y + c0.y + e0.y, a0.z + c0.z + e0.z, a0.w + c0.w + e0.w,
                          a1.x + c1.x + e1.x, a1.y + c1.y + e1.y, a1.z + c1.z + e1.z, a1.w + c1.w + e1.w};
            float r[8] = {0.f,0.f,0.f,0.f,0.f,0.f,0.f,0.f};
            if constexpr (MODE == 2) {
                const float* rp = rsum + (size_t)row * 64 + fb;
                float4 r0 = *(const float4*)(rp); float4 r1 = *(const float4*)(rp + 4);
                r[0]=r0.x; r[1]=r0.y; r[2]=r0.z; r[3]=r0.w;
                r[4]=r1.x; r[5]=r1.y; r[6]=r1.z; r[7]=r1.w;
            }
            #pragma unroll
            for (int j = 0; j < 8; ++j) {
                float v = m[j] * (1.f / 3.f);
                v = (v > 0.f) ? v : (fast_exp2(v * LOG2E) - 1.f);   // ELU
                sf[ks][j] = v + r[j];
            }
        }
        __syncthreads();           // all rsum reads done before any write
        if (fg == 0) {
            #pragma unroll
            for (int ks = 0; ks < 2; ++ks) {
                float* rp = rsum + (size_t)row * 64 + ks * 32 + l4 * 8;
                *(float4*)(rp)     = make_float4(sf[ks][0], sf[ks][1], sf[ks][2], sf[ks][3]);
                *(float4*)(rp + 4) = make_float4(sf[ks][4], sf[ks][5], sf[ks][6], sf[ks][7]);
            }
        }
        #pragma unroll
        for (int ks = 0; ks < 2; ++ks) {
            union { unsigned u[4]; bf16x8 v; } uu;
            #pragma unroll
            for (int jj = 0; jj < 4; ++jj)
                uu.u[jj] = cvt_pk_bf16(sf[ks][2 * jj], sf[ks][2 * jj + 1]);
            afr[ks] = uu.v;
        }
    }

    f32x4 acc[3] = {(f32x4)0.f, (f32x4)0.f, (f32x4)0.f};
    f32x4 sdacc  = (f32x4)0.f;
    #pragma unroll
    for (int ks = 0; ks < NK; ++ks) {
        int k = ks * 32 + l4 * 8;
        #pragma unroll
        for (int t = 0; t < 3; ++t) {
            int n = (fg * 3 + t) * 16 + l15;
            bf16x8 bf = *(const bf16x8*)(WT + (size_t)n * KDIM + k);
            acc[t] = __builtin_amdgcn_mfma_f32_16x16x32_bf16(afr[ks], bf, acc[t], 0, 0, 0);
        }
        if (fg == 0) {
            bf16x8 bsd = *(const bf16x8*)(WsdT + (size_t)l15 * KDIM + k);
            sdacc = __builtin_amdgcn_mfma_f32_16x16x32_bf16(afr[ks], bsd, sdacc, 0, 0, 0);
        }
    }
    #pragma unroll
    for (int t = 0; t < 3; ++t) {
        int hf = (fg * 3 + t) * 16 + l15;
        size_t base = ((size_t)(b * 3 + (hf >> 6)) * 64 + (hf & 63)) * 1024 + nbase + l4 * 4;
        uint2 pk;
        pk.x = cvt_pk_bf16(acc[t][0], acc[t][1]);
        pk.y = cvt_pk_bf16(acc[t][2], acc[t][3]);
        *(uint2*)(VT + base) = pk;
    }
    if (fg == 0 && l15 < 6) {
        int h = l15 >> 1;
        float* dst = (l15 & 1) ? dt : st;
        size_t base = (size_t)(b * 3 + h) * 1024 + nbase + l4 * 4;
        #pragma unroll
        for (int r = 0; r < 4; ++r) dst[base + r] = sdacc[r];
    }
}

// ---------------------------------------------------------------------------
// Attention, factored-exp form. Per-row scale-invariance of softmax:
//   p'_ij = mask * max(F1_j, R_i * F2_j)
//   F1 = exp(d), F2 = exp(0.2 d)  (staged in LDS, computed once per block)
//   R  = exp(-0.8 s)              (per-row register)
// equals exp(leaky(s+d)) / exp(s)  -> identical softmax. NO exp in the loop.
// Grid 768 XCD-swizzled (b = blk&7); block 256 = 4 waves, wave w covers
// j in [w*256,(w+1)*256) (8 iters), full 32x64 partial; LDS combine.
// ---------------------------------------------------------------------------
__global__ __launch_bounds__(256) void attn_head_kernel(
    const unsigned short* __restrict__ VT,
    const float* __restrict__ st, const float* __restrict__ dt,
    const unsigned int* __restrict__ maskw,   // [1024 rows][32 words]
    float* __restrict__ hacc)                 // [b][1024][192]
{
    __shared__ float F1lds[1024];
    __shared__ float F2lds[1024];
    __shared__ unsigned int lmask[32 * 33];
    __shared__ float pO[4][32 * 68];
    __shared__ float pZ[4][32];

    int b     = blockIdx.x & 7;               // = XCD
    int q     = blockIdx.x >> 3;              // 0..95
    int h     = q >> 5;
    int bh    = b * 3 + h;
    int ibase = (q & 31) << 5;
    int w = threadIdx.x >> 6, l = threadIdx.x & 63;
    int l15 = l & 15, l4 = l >> 4;

    // stage mask words (stride 33) and F1/F2
    #pragma unroll
    for (int i = 0; i < 4; ++i) {
        int idx = threadIdx.x + i * 256;
        int row = idx >> 5, wd = idx & 31;
        lmask[row * 33 + wd] = maskw[(size_t)(ibase + row) * 32 + wd];
    }
    {
        int t4 = threadIdx.x * 4;
        float4 dv4 = *(const float4*)(dt + (size_t)bh * 1024 + t4);
        *(float4*)(F1lds + t4) = make_float4(
            fast_exp2(dv4.x * LOG2E), fast_exp2(dv4.y * LOG2E),
            fast_exp2(dv4.z * LOG2E), fast_exp2(dv4.w * LOG2E));
        *(float4*)(F2lds + t4) = make_float4(
            fast_exp2(dv4.x * (0.2f * LOG2E)), fast_exp2(dv4.y * (0.2f * LOG2E)),
            fast_exp2(dv4.z * (0.2f * LOG2E)), fast_exp2(dv4.w * (0.2f * LOG2E)));
    }
    __syncthreads();

    float R0 = fast_exp2(st[(size_t)bh * 1024 + ibase + l15]      * (-0.8f * LOG2E));
    float R1 = fast_exp2(st[(size_t)bh * 1024 + ibase + 16 + l15] * (-0.8f * LOG2E));
    const unsigned short* vbase = VT + (size_t)bh * 64 * 1024;

    f32x4 acc[2][4];
    #pragma unroll
    for (int rg = 0; rg < 2; ++rg)
        #pragma unroll
        for (int f4 = 0; f4 < 4; ++f4) acc[rg][f4] = (f32x4)0.f;
    float z0 = 0.f, z1 = 0.f;
    int jb = w * 256;
    int w8 = w * 8;

    auto ldstep = [&](int it, float4& F1a, float4& F1b, float4& F2a, float4& F2b,
                      bf16x8& Va, bf16x8& Vb, bf16x8& Vc, bf16x8& Vd) {
        int kk = jb + it * 32 + l4 * 8;
        F1a = *(const float4*)(F1lds + kk);
        F1b = *(const float4*)(F1lds + kk + 4);
        F2a = *(const float4*)(F2lds + kk);
        F2b = *(const float4*)(F2lds + kk + 4);
        Va = *(const bf16x8*)(vbase + (size_t)(l15)      * 1024 + kk);
        Vb = *(const bf16x8*)(vbase + (size_t)(16 + l15) * 1024 + kk);
        Vc = *(const bf16x8*)(vbase + (size_t)(32 + l15) * 1024 + kk);
        Vd = *(const bf16x8*)(vbase + (size_t)(48 + l15) * 1024 + kk);
    };
    auto cstep = [&](int it, float4 F1a, float4 F1b, float4 F2a, float4 F2b,
                     bf16x8 Va, bf16x8 Vb, bf16x8 Vc, bf16x8 Vd) {
        unsigned m0 = (lmask[l15 * 33 + w8 + it]        >> (l4 * 8)) & 0xffu;
        unsigned m1 = (lmask[(16 + l15) * 33 + w8 + it] >> (l4 * 8)) & 0xffu;
        float f1[8] = {F1a.x, F1a.y, F1a.z, F1a.w, F1b.x, F1b.y, F1b.z, F1b.w};
        float f2[8] = {F2a.x, F2a.y, F2a.z, F2a.w, F2b.x, F2b.y, F2b.z, F2b.w};
        float p0[8], p1[8];
        #pragma unroll
        for (int j = 0; j < 8; ++j) {
            float a0 = fmaxf(f1[j], R0 * f2[j]);
            p0[j] = ((m0 >> j) & 1) ? a0 : 0.f;
            z0 += p0[j];
            float a1 = fmaxf(f1[j], R1 * f2[j]);
            p1[j] = ((m1 >> j) & 1) ? a1 : 0.f;
            z1 += p1[j];
        }
        union { unsigned u[4]; bf16x8 v; } ua, ub;
        #pragma unroll
        for (int jj = 0; jj < 4; ++jj) {
            ua.u[jj] = cvt_pk_bf16(p0[2 * jj], p0[2 * jj + 1]);
            ub.u[jj] = cvt_pk_bf16(p1[2 * jj], p1[2 * jj + 1]);
        }
        acc[0][0] = __builtin_amdgcn_mfma_f32_16x16x32_bf16(ua.v, Va, acc[0][0], 0, 0, 0);
        acc[0][1] = __builtin_amdgcn_mfma_f32_16x16x32_bf16(ua.v, Vb, acc[0][1], 0, 0, 0);
        acc[0][2] = __builtin_amdgcn_mfma_f32_16x16x32_bf16(ua.v, Vc, acc[0][2], 0, 0, 0);
        acc[0][3] = __builtin_amdgcn_mfma_f32_16x16x32_bf16(ua.v, Vd, acc[0][3], 0, 0, 0);
        acc[1][0] = __builtin_amdgcn_mfma_f32_16x16x32_bf16(ub.v, Va, acc[1][0], 0, 0, 0);
        acc[1][1] = __builtin_amdgcn_mfma_f32_16x16x32_bf16(ub.v, Vb, acc[1][1], 0, 0, 0);
        acc[1][2] = __builtin_amdgcn_mfma_f32_16x16x32_bf16(ub.v, Vc, acc[1][2], 0, 0, 0);
        acc[1][3] = __builtin_amdgcn_mfma_f32_16x16x32_bf16(ub.v, Vd, acc[1][3], 0, 0, 0);
    };

    // 2-stage software pipeline over 8 iterations
    float4 F1a0, F1b0, F2a0, F2b0, F1a1, F1b1, F2a1, F2b1;
    bf16x8 Va0, Vb0, Vc0, Vd0, Va1, Vb1, Vc1, Vd1;
    ldstep(0, F1a0, F1b0, F2a0, F2b0, Va0, Vb0, Vc0, Vd0);
    #pragma unroll
    for (int it = 0; it < 8; it += 2) {
        if (it + 1 < 8) ldstep(it + 1, F1a1, F1b1, F2a1, F2b1, Va1, Vb1, Vc1, Vd1);
        cstep(it, F1a0, F1b0, F2a0, F2b0, Va0, Vb0, Vc0, Vd0);
        if (it + 2 < 8) ldstep(it + 2, F1a0, F1b0, F2a0, F2b0, Va0, Vb0, Vc0, Vd0);
        if (it + 1 < 8) cstep(it + 1, F1a1, F1b1, F2a1, F2b1, Va1, Vb1, Vc1, Vd1);
    }

    z0 += __shfl_xor(z0, 16); z0 += __shfl_xor(z0, 32);
    z1 += __shfl_xor(z1, 16); z1 += __shfl_xor(z1, 32);
    if (l4 == 0) pZ[w][l15] = z0;
    if (l4 == 1) pZ[w][16 + l15] = z1;
    #pragma unroll
    for (int rg = 0; rg < 2; ++rg)
        #pragma unroll
        for (int f4 = 0; f4 < 4; ++f4)
            #pragma unroll
            for (int r = 0; r < 4; ++r)
                pO[w][(rg * 16 + l4 * 4 + r) * 68 + f4 * 16 + l15] = acc[rg][f4][r];
    __syncthreads();

    int row = threadIdx.x >> 3;
    int fo  = (threadIdx.x & 7) * 8;
    float zs = pZ[0][row] + pZ[1][row] + pZ[2][row] + pZ[3][row];
    float rcp = 1.f / ((zs == 0.f) ? 1.f : zs);
    float o[8] = {0.f,0.f,0.f,0.f,0.f,0.f,0.f,0.f};
    #pragma unroll
    for (int ww = 0; ww < 4; ++ww) {
        const float* pp = &pO[ww][row * 68 + fo];
        float4 a = *(const float4*)(pp);
        float4 c = *(const float4*)(pp + 4);
        o[0] += a.x; o[1] += a.y; o[2] += a.z; o[3] += a.w;
        o[4] += c.x; o[5] += c.y; o[6] += c.z; o[7] += c.w;
    }
    float* op = hacc + (size_t)(b * 1024 + ibase + row) * 192 + h * 64 + fo;
    *(float4*)(op)     = make_float4(o[0] * rcp, o[1] * rcp, o[2] * rcp, o[3] * rcp);
    *(float4*)(op + 4) = make_float4(o[4] * rcp, o[5] * rcp, o[6] * rcp, o[7] * rcp);
}

// ---------------------------------------------------------------------------
// GRU + heads fused. sf2 = rsum + ELU(mean(hacc2)) built in-register;
// gi = sf2@wi.T, gh = hp16@wh.T; gates fp32; hnew written; hn bf16 staged in
// LDS; then actor/critic heads (path = w>>1). Grid 256, XCD-swizzled.
// ---------------------------------------------------------------------------
__global__ __launch_bounds__(256) void gruheads_kernel(
    const float* __restrict__ haccp, const float* __restrict__ rsum,
    const unsigned short* __restrict__ hp16,
    const unsigned short* __restrict__ wi16, const unsigned short* __restrict__ wh16,
    const float* __restrict__ bi, const float* __restrict__ bh,
    const float* __restrict__ hprev,
    const unsigned short* __restrict__ Wa1T, const unsigned short* __restrict__ Wc1T,
    const float* __restrict__ ba1, const float* __restrict__ Wa2, const float* __restrict__ ba2,
    const float* __restrict__ bc1, const float* __restrict__ Wc2, const float* __restrict__ bc2,
    float* __restrict__ hnew, float* __restrict__ probs, float* __restrict__ value)
{
    __shared__ unsigned short hnlds[32 * 72];

    int b     = blockIdx.x & 7;
    int nbase = (int)(blockIdx.x >> 3) << 5;
    int w = threadIdx.x >> 6, l = threadIdx.x & 63;
    int rh = w & 1, g = w >> 1;
    int l15 = l & 15, l4 = l >> 4;
    int rowbase = b * 1024 + nbase + rh * 16;
    int arow = rowbase + l15;

    // build sf2 A-frags
    bf16x8 ai[2];
    #pragma unroll
    for (int ks = 0; ks < 2; ++ks) {
        int fb = ks * 32 + l4 * 8;
        const float* hp = haccp + (size_t)arow * 192 + fb;
        float4 a0 = *(const float4*)(hp);       float4 a1 = *(const float4*)(hp + 4);
        float4 c0 = *(const float4*)(hp + 64);  float4 c1 = *(const float4*)(hp + 68);
        float4 e0 = *(const float4*)(hp + 128); float4 e1 = *(const float4*)(hp + 132);
        const float* rp = rsum + (size_t)arow * 64 + fb;
        float4 r0 = *(const float4*)(rp);       float4 r1 = *(const float4*)(rp + 4);
        float m[8] = {a0.x + c0.x + e0.x, a0.y + c0.y + e0.y, a0.z + c0.z + e0.z, a0.w + c0.w + e0.w,
                      a1.x + c1.x + e1.x, a1.y + c1.y + e1.y, a1.z + c1.z + e1.z, a1.w + c1.w + e1.w};
        float rr[8] = {r0.x, r0.y, r0.z, r0.w, r1.x, r1.y, r1.z, r1.w};
        float sf[8];
        #pragma unroll
        for (int j = 0; j < 8; ++j) {
            float v = m[j] * (1.f / 3.f);
            v = (v > 0.f) ? v : (fast_exp2(v * LOG2E) - 1.f);
            sf[j] = v + rr[j];
        }
        union { unsigned u[4]; bf16x8 v; } uu;
        #pragma unroll
        for (int jj = 0; jj < 4; ++jj)
            uu.u[jj] = cvt_pk_bf16(sf[2 * jj], sf[2 * jj + 1]);
        ai[ks] = uu.v;
    }

    f32x4 gi[2][3], gh[2][3];
    #pragma unroll
    for (int t = 0; t < 2; ++t)
        #pragma unroll
        for (int q = 0; q < 3; ++q) { gi[t][q] = (f32x4)0.f; gh[t][q] = (f32x4)0.f; }

    #pragma unroll
    for (int ks = 0; ks < 2; ++ks) {
        int k = ks * 32 + l4 * 8;
        bf16x8 ah = *(const bf16x8*)(hp16 + (size_t)arow * 64 + k);
        #pragma unroll
        for (int t = 0; t < 2; ++t) {
            #pragma unroll
            for (int q = 0; q < 3; ++q) {
                int n = (q * 4 + g * 2 + t) * 16 + l15;
                bf16x8 bwi = *(const bf16x8*)(wi16 + (size_t)n * 64 + k);
                bf16x8 bwh = *(const bf16x8*)(wh16 + (size_t)n * 64 + k);
                gi[t][q] = __builtin_amdgcn_mfma_f32_16x16x32_bf16(ai[ks], bwi, gi[t][q], 0, 0, 0);
                gh[t][q] = __builtin_amdgcn_mfma_f32_16x16x32_bf16(ah,     bwh, gh[t][q], 0, 0, 0);
            }
        }
    }
    #pragma unroll
    for (int t = 0; t < 2; ++t) {
        int c = (g * 2 + t) * 16 + l15;
        float bir = bi[c], biz = bi[64 + c], bin = bi[128 + c];
        float bhr = bh[c], bhz = bh[64 + c], bhn = bh[128 + c];
        #pragma unroll
        for (int r = 0; r < 4; ++r) {
            int rloc = rh * 16 + 4 * l4 + r;
            int row = b * 1024 + nbase + rloc;
            float rr = (gi[t][0][r] + bir) + (gh[t][0][r] + bhr);
            float zz = (gi[t][1][r] + biz) + (gh[t][1][r] + bhz);
            float rg = 1.f / (1.f + fast_exp2(-rr * LOG2E));
            float zg = 1.f / (1.f + fast_exp2(-zz * LOG2E));
            float narg = (gi[t][2][r] + bin) + rg * (gh[t][2][r] + bhn);
            narg = fminf(fmaxf(narg, -15.f), 15.f);
            float e2 = fast_exp2(2.f * narg * LOG2E);
            float ng = (e2 - 1.f) / (e2 + 1.f);
            float hp = hprev[(size_t)row * 64 + c];
            float hv = (1.f - zg) * ng + zg * hp;
            hnew[(size_t)row * 64 + c] = hv;
            hnlds[rloc * 72 + c] = f2bf(hv);
        }
    }
    __syncthreads();

    // heads phase: path = g; waves (rh) cover both row halves
    const unsigned short* WT = g ? Wc1T : Wa1T;
    f32x4 acc[2] = {(f32x4)0.f, (f32x4)0.f};
    #pragma unroll
    for (int ks = 0; ks < 2; ++ks) {
        int k = ks * 32 + l4 * 8;
        bf16x8 a = *(const bf16x8*)(&hnlds[(rh * 16 + l15) * 72 + k]);
        #pragma unroll
        for (int t = 0; t < 2; ++t) {
            bf16x8 bf = *(const bf16x8*)(WT + (size_t)(t * 16 + l15) * 64 + k);
            acc[t] = __builtin_amdgcn_mfma_f32_16x16x32_bf16(a, bf, acc[t], 0, 0, 0);
        }
    }
    int rowbase2 = b * 1024 + nbase + rh * 16;
    if (g == 0) {
        float p0[4] = {0.f,0.f,0.f,0.f}, p1[4] = {0.f,0.f,0.f,0.f};
        #pragma unroll
        for (int t = 0; t < 2; ++t) {
            int c = t * 16 + l15;
            float b1 = ba1[c], w20 = Wa2[c * 2], w21 = Wa2[c * 2 + 1];
            #pragma unroll
            for (int r = 0; r < 4; ++r) {
                float v = fmaxf(acc[t][r] + b1, 0.f);
                p0[r] += v * w20; p1[r] += v * w21;
            }
        }
        #pragma unroll
        for (int r = 0; r < 4; ++r) {
            #pragma unroll
            for (int off = 1; off < 16; off <<= 1) {
                p0[r] += __shfl_xor(p0[r], off);
                p1[r] += __shfl_xor(p1[r], off);
            }
            float l0 = p0[r] + ba2[0], l1 = p1[r] + ba2[1];
            float mm = fmaxf(l0, l1);
            float e0 = fast_exp2((l0 - mm) * LOG2E);
            float e1 = fast_exp2((l1 - mm) * LOG2E);
            float s = 1.f / (e0 + e1);
            if (l15 == 0) {
                int row = rowbase2 + 4 * l4 + r;
                probs[(size_t)row * 2]     = e0 * s;
                probs[(size_t)row * 2 + 1] = e1 * s;
            }
        }
    } else {
        float pv[4] = {0.f,0.f,0.f,0.f};
        #pragma unroll
        for (int t = 0; t < 2; ++t) {
            int c = t * 16 + l15;
            float b1 = bc1[c], w2 = Wc2[c];
            #pragma unroll
            for (int r = 0; r < 4; ++r) {
                float v = fmaxf(acc[t][r] + b1, 0.f);
                pv[r] += v * w2;
            }
        }
        #pragma unroll
        for (int r = 0; r < 4; ++r) {
            #pragma unroll
            for (int off = 1; off < 16; off <<= 1) pv[r] += __shfl_xor(pv[r], off);
            if (l15 == 0) {
                int row = rowbase2 + 4 * l4 + r;
                value[row] = pv[r] + bc2[0];
            }
        }
    }
}

// ---------------------------------------------------------------------------
extern "C" void kernel_launch(void* const* d_in, const int* in_sizes, int n_in,
                              void* d_out, int out_size, void* d_ws, size_t ws_size,
                              hipStream_t stream)
{
    const float* x      = (const float*)d_in[0];
    const int*   adj    = (const int*)d_in[1];
    const float* h_prev = (const float*)d_in[2];
    const float* W0  = (const float*)d_in[3];
    const float* as0 = (const float*)d_in[4];
    const float* ad0 = (const float*)d_in[5];
    const float* W1  = (const float*)d_in[6];
    const float* as1 = (const float*)d_in[7];
    const float* ad1 = (const float*)d_in[8];
    const float* W2  = (const float*)d_in[9];
    const float* as2 = (const float*)d_in[10];
    const float* ad2 = (const float*)d_in[11];
    const float* gwi = (const float*)d_in[12];
    const float* gwh = (const float*)d_in[13];
    const float* gbi = (const float*)d_in[14];
    const float* gbh = (const float*)d_in[15];
    const float* Wa1 = (const float*)d_in[16];
    const float* ba1 = (const float*)d_in[17];
    const float* Wa2 = (const float*)d_in[18];
    const float* ba2 = (const float*)d_in[19];
    const float* Wc1 = (const float*)d_in[20];
    const float* bc1 = (const float*)d_in[21];
    const float* Wc2 = (const float*)d_in[22];
    const float* bc2 = (const float*)d_in[23];

    float* out   = (float*)d_out;
    float* probs = out;            // (8,1024,2)
    float* value = out + 16384;    // (8,1024,1)
    float* hnew  = out + 24576;    // (8,1024,64)

    char* p = (char*)d_ws;
    auto alloc = [&](size_t bytes) { char* q = p; p += (bytes + 255) & ~(size_t)255; return q; };
    auto* maskb = (unsigned long long*)alloc(16384 * 8);
    auto*  xpad  = (unsigned short*)alloc((size_t)NROWS * 32 * 2);
    auto*  hp16  = (unsigned short*)alloc((size_t)NROWS * 64 * 2);
    auto*  VT    = (unsigned short*)alloc((size_t)BB * 3 * 64 * 1024 * 2);
    float* st    = (float*)alloc((size_t)BB * 3 * 1024 * 4);
    float* dt    = (float*)alloc((size_t)BB * 3 * 1024 * 4);
    float* hacc  = (float*)alloc((size_t)BB * 1024 * 192 * 4);
    float* rsum  = (float*)alloc((size_t)NROWS * 64 * 4);
    auto*  W0Tp  = (unsigned short*)alloc(192 * 32 * 2);
    auto*  W1T   = (unsigned short*)alloc(192 * 64 * 2);
    auto*  W2T   = (unsigned short*)alloc(192 * 64 * 2);
    auto*  wi16  = (unsigned short*)alloc(192 * 64 * 2);
    auto*  wh16  = (unsigned short*)alloc(192 * 64 * 2);
    auto*  Wa1T  = (unsigned short*)alloc(32 * 64 * 2);
    auto*  Wc1T  = (unsigned short*)alloc(32 * 64 * 2);
    auto*  Wsd0  = (unsigned short*)alloc(16 * 32 * 2);
    auto*  Wsd1  = (unsigned short*)alloc(16 * 64 * 2);
    auto*  Wsd2  = (unsigned short*)alloc(16 * 64 * 2);
    (void)ws_size; (void)in_sizes; (void)n_in; (void)out_size;

    const unsigned int* maskw = (const unsigned int*)maskb;

    setup_kernel<<<1024, 256, 0, stream>>>(
        x, adj, h_prev, W0, as0, ad0, W1, as1, ad1, W2, as2, ad2,
        gwi, gwh, Wa1, Wc1,
        maskb, xpad, hp16, W0Tp, W1T, W2T, wi16, wh16, Wa1T, Wc1T,
        Wsd0, Wsd1, Wsd2);

    // Layer 0
    proj_kernel<32, 0><<<512, 256, 0, stream>>>(xpad, nullptr, nullptr, W0Tp, Wsd0, VT, st, dt);
    attn_head_kernel<<<768, 256, 0, stream>>>(VT, st, dt, maskw, hacc);
    // Layer 1: proj fuses combine of layer0 (rsum := E0)
    proj_kernel<64, 1><<<512, 256, 0, stream>>>(nullptr, hacc, rsum, W1T, Wsd1, VT, st, dt);
    attn_head_kernel<<<768, 256, 0, stream>>>(VT, st, dt, maskw, hacc);
    // Layer 2: proj fuses combine of layer1 (rsum := E0+E1)
    proj_kernel<64, 2><<<512, 256, 0, stream>>>(nullptr, hacc, rsum, W2T, Wsd2, VT, st, dt);
    attn_head_kernel<<<768, 256, 0, stream>>>(VT, st, dt, maskw, hacc);
    // GRU + heads (fuses combine of layer2)
    gruheads_kernel<<<256, 256, 0, stream>>>(
        hacc, rsum, hp16, wi16, wh16, gbi, gbh, h_prev,
        Wa1T, Wc1T, ba1, Wa2, ba2, bc1, Wc2, bc2, hnew, probs, value);
}